// Round 7
// baseline (576.498 us; speedup 1.0000x reference)
//
#include <hip/hip_runtime.h>
#include <hip/hip_bf16.h>

// Problem constants
#define BB 8
#define NN 4096
#define EE 65536            // edges per graph
#define BE (BB*EE)          // 524288 total edges
#define BN (BB*NN)          // 32768 total nodes
#define INF 128
#define HID 512
#define CC 2
#define OUTC 10

typedef __bf16 bf16x8_t __attribute__((ext_vector_type(8)));
typedef float  f32x4_t  __attribute__((ext_vector_type(4)));

__device__ __forceinline__ ushort f2bf(float f) {
  union { float f; unsigned u; } v; v.f = f;
  unsigned r = v.u + 0x7FFFu + ((v.u >> 16) & 1u);   // RNE
  return (ushort)(r >> 16);
}
__device__ __forceinline__ float bf2f(ushort s) {
  union { unsigned u; float f; } v; v.u = ((unsigned)s) << 16;
  return v.f;
}

// ---------------------------------------------------------------------------
// Kernel A (fused edge pipeline): owner-computes aggregation, no CSR.
// Grid 512 = (graph b = blk&7, node-range r = blk>>3, 64 nodes each).
// Block scans graph-b dst (int4), lists its owned edges (~1024, cap 2048 =
// +32 sigma), then wave-parallel accumulates w*x[src,:] into an LDS fp32
// tile via ds_add_f32, and stores the bf16 A-slab. Zero global atomics.
// ---------------------------------------------------------------------------
__global__ __launch_bounds__(256) void fused_agg(
    const int* __restrict__ src, const int* __restrict__ dst,
    const float* __restrict__ ew, const float* __restrict__ x,
    ushort* __restrict__ Ab) {
  __shared__ float lacc[64 * 128];     // 32 KB
  __shared__ int   lidx[2048];         // 8 KB
  __shared__ int   lcount;
  int blk = blockIdx.x;
  int b = blk & 7, r = blk >> 3;
  int nbase = b * NN + r * 64;         // first global node owned
  int t = threadIdx.x;
  for (int i = t; i < 64 * 128; i += 256) lacc[i] = 0.f;
  if (t == 0) lcount = 0;
  __syncthreads();

  // scan dst, collect owned edges (packed: edge_local | local_dst<<16)
  const int4* d4 = (const int4*)(dst + (size_t)b * EE);
  for (int i = t; i < EE / 4; i += 256) {
    int4 v = d4[i];
    int a;
    a = v.x - nbase; if ((unsigned)a < 64u) { int p = atomicAdd(&lcount, 1); if (p < 2048) lidx[p] = (i * 4 + 0) | (a << 16); }
    a = v.y - nbase; if ((unsigned)a < 64u) { int p = atomicAdd(&lcount, 1); if (p < 2048) lidx[p] = (i * 4 + 1) | (a << 16); }
    a = v.z - nbase; if ((unsigned)a < 64u) { int p = atomicAdd(&lcount, 1); if (p < 2048) lidx[p] = (i * 4 + 2) | (a << 16); }
    a = v.w - nbase; if ((unsigned)a < 64u) { int p = atomicAdd(&lcount, 1); if (p < 2048) lidx[p] = (i * 4 + 3) | (a << 16); }
  }
  __syncthreads();
  int cnt = lcount; if (cnt > 2048) cnt = 2048;

  // wave-parallel accumulation, 4x unrolled for memory-level parallelism
  int wave = t >> 6, lane = t & 63;
  int jbeg = (cnt * wave) >> 2;
  int jend = (cnt * (wave + 1)) >> 2;
  size_t e0 = (size_t)b * EE;
  int j = jbeg;
  for (; j + 3 < jend; j += 4) {
    int pk0 = lidx[j], pk1 = lidx[j + 1], pk2 = lidx[j + 2], pk3 = lidx[j + 3];
    int sg0 = src[e0 + (pk0 & 0xFFFF)], sg1 = src[e0 + (pk1 & 0xFFFF)];
    int sg2 = src[e0 + (pk2 & 0xFFFF)], sg3 = src[e0 + (pk3 & 0xFFFF)];
    float w0 = ew[e0 + (pk0 & 0xFFFF)], w1 = ew[e0 + (pk1 & 0xFFFF)];
    float w2 = ew[e0 + (pk2 & 0xFFFF)], w3 = ew[e0 + (pk3 & 0xFFFF)];
    float2 x0 = *(const float2*)&x[(size_t)sg0 * INF + lane * 2];
    float2 x1 = *(const float2*)&x[(size_t)sg1 * INF + lane * 2];
    float2 x2 = *(const float2*)&x[(size_t)sg2 * INF + lane * 2];
    float2 x3 = *(const float2*)&x[(size_t)sg3 * INF + lane * 2];
    int d0 = (pk0 >> 16) * 128 + lane * 2, d1 = (pk1 >> 16) * 128 + lane * 2;
    int d2 = (pk2 >> 16) * 128 + lane * 2, d3 = (pk3 >> 16) * 128 + lane * 2;
    atomicAdd(&lacc[d0], w0 * x0.x); atomicAdd(&lacc[d0 + 1], w0 * x0.y);
    atomicAdd(&lacc[d1], w1 * x1.x); atomicAdd(&lacc[d1 + 1], w1 * x1.y);
    atomicAdd(&lacc[d2], w2 * x2.x); atomicAdd(&lacc[d2 + 1], w2 * x2.y);
    atomicAdd(&lacc[d3], w3 * x3.x); atomicAdd(&lacc[d3 + 1], w3 * x3.y);
  }
  for (; j < jend; ++j) {
    int pk = lidx[j];
    int sg = src[e0 + (pk & 0xFFFF)];
    float w = ew[e0 + (pk & 0xFFFF)];
    float2 xv = *(const float2*)&x[(size_t)sg * INF + lane * 2];
    int d = (pk >> 16) * 128 + lane * 2;
    atomicAdd(&lacc[d], w * xv.x);
    atomicAdd(&lacc[d + 1], w * xv.y);
  }
  __syncthreads();

  // store bf16 A-slab (64 nodes x 128 feats)
  for (int i = t; i < 64 * 64; i += 256) {
    int row = i >> 6, f2 = i & 63;
    ushort2 o;
    o.x = f2bf(lacc[row * 128 + f2 * 2]);
    o.y = f2bf(lacc[row * 128 + f2 * 2 + 1]);
    *(ushort2*)&Ab[(size_t)(nbase + row) * 256 + f2 * 2] = o;
  }
}

// ---------------------------------------------------------------------------
// Kernel A5: cast x -> A[:, 128:256] bf16.  One float4 per thread.
// ---------------------------------------------------------------------------
__global__ __launch_bounds__(256) void cast_x(
    const float* __restrict__ x, ushort* __restrict__ Ab) {
  int g = blockIdx.x * 256 + threadIdx.x;        // 0..1048575
  float4 v = *(const float4*)&x[(size_t)g * 4];
  int m = g >> 5;
  int kin = (g & 31) * 4;
  ushort4 o;
  o.x = f2bf(v.x); o.y = f2bf(v.y); o.z = f2bf(v.z); o.w = f2bf(v.w);
  *(ushort4*)&Ab[(size_t)m * 256 + 128 + kin] = o;
}

// ---------------------------------------------------------------------------
// Kernel A6: Bb[n][k] = bf16 of [Wrel1;Wroot1][k][n]  (pre-transposed weights)
// ---------------------------------------------------------------------------
__global__ __launch_bounds__(256) void cast_w(
    const float* __restrict__ Wrel, const float* __restrict__ Wroot,
    ushort* __restrict__ Bb) {
  int g = blockIdx.x * 256 + threadIdx.x;        // 0..131071
  int n = g & 511, k = g >> 9;
  float w = (k < 128) ? Wrel[k * 512 + n] : Wroot[(k - 128) * 512 + n];
  Bb[n * 256 + k] = f2bf(w);
}

// ---------------------------------------------------------------------------
// Kernel C: MFMA GEMM  h = relu(A(32768x256) @ B(256x512) + b), bf16 in/out.
// 128x128 tile, 4 waves, 16x16x32 bf16 MFMA, BK=32, XCD-swizzled grid.
// ---------------------------------------------------------------------------
#define LDA 40
__global__ __launch_bounds__(256) void gemm_mfma(
    const ushort* __restrict__ Ab, const ushort* __restrict__ Bb,
    const float* __restrict__ brel, ushort* __restrict__ hw) {
  __shared__ ushort As[128 * LDA];
  __shared__ ushort Bs[128 * LDA];
  int tid = threadIdx.x;
  int blk = blockIdx.x;
  int xcd = blk & 7;
  int idx = blk >> 3;              // 0..127
  int by = xcd * 32 + (idx & 31);  // 0..255
  int bx = idx >> 5;               // 0..3
  int m0 = by * 128, n0 = bx * 128;
  int wave = tid >> 6, lane = tid & 63;
  int wm = (wave >> 1) * 64, wn = (wave & 1) * 64;
  int l16 = lane & 15, quad = lane >> 4;

  f32x4_t acc[4][4];
#pragma unroll
  for (int i = 0; i < 4; ++i)
#pragma unroll
    for (int j = 0; j < 4; ++j) acc[i][j] = (f32x4_t){0.f, 0.f, 0.f, 0.f};

  int r0 = tid >> 2,          k0 = (tid & 3) * 8;
  int r1 = (tid + 256) >> 2,  k1 = (tid & 3) * 8;

  int aoff[4], boff[4];
#pragma unroll
  for (int i = 0; i < 4; ++i) {
    aoff[i] = (wm + i * 16 + l16) * LDA + quad * 8;
    boff[i] = (wn + i * 16 + l16) * LDA + quad * 8;
  }

  for (int kc = 0; kc < 256; kc += 32) {
    *(uint4*)&As[r0 * LDA + k0] = *(const uint4*)&Ab[(size_t)(m0 + r0) * 256 + kc + k0];
    *(uint4*)&As[r1 * LDA + k1] = *(const uint4*)&Ab[(size_t)(m0 + r1) * 256 + kc + k1];
    *(uint4*)&Bs[r0 * LDA + k0] = *(const uint4*)&Bb[(size_t)(n0 + r0) * 256 + kc + k0];
    *(uint4*)&Bs[r1 * LDA + k1] = *(const uint4*)&Bb[(size_t)(n0 + r1) * 256 + kc + k1];
    __syncthreads();
    bf16x8_t af[4], bf[4];
#pragma unroll
    for (int i = 0; i < 4; ++i) {
      af[i] = *(const bf16x8_t*)&As[aoff[i]];
      bf[i] = *(const bf16x8_t*)&Bs[boff[i]];
    }
#pragma unroll
    for (int mt = 0; mt < 4; ++mt)
#pragma unroll
      for (int nt = 0; nt < 4; ++nt)
        acc[mt][nt] = __builtin_amdgcn_mfma_f32_16x16x32_bf16(af[mt], bf[nt], acc[mt][nt], 0, 0, 0);
    __syncthreads();
  }

#pragma unroll
  for (int nt = 0; nt < 4; ++nt) {
    int col = n0 + wn + nt * 16 + l16;
    float bias = brel[col];
#pragma unroll
    for (int mt = 0; mt < 4; ++mt) {
      int rowb = m0 + wm + mt * 16 + quad * 4;
#pragma unroll
      for (int r = 0; r < 4; ++r) {
        float v = fmaxf(acc[mt][nt][r] + bias, 0.f);
        hw[(size_t)(rowb + r) * 512 + col] = f2bf(v);
      }
    }
  }
}

// ---------------------------------------------------------------------------
// Kernel D: s_logits = h @ W_pool + b_pool ; s = softmax(s_logits). h is bf16.
// ---------------------------------------------------------------------------
__global__ __launch_bounds__(256) void pool_softmax(
    const ushort* __restrict__ hw, const float* __restrict__ Wp,
    const float* __restrict__ bp, float* __restrict__ s,
    float* __restrict__ slog) {
  __shared__ float wp0[HID], wp1[HID];
  int tid = threadIdx.x;
  for (int i = tid; i < HID; i += 256) {
    wp0[i] = Wp[i * 2];
    wp1[i] = Wp[i * 2 + 1];
  }
  __syncthreads();
  int wave = tid >> 6, lane = tid & 63;
  int n = blockIdx.x * 4 + wave;
  float acc0 = 0.f, acc1 = 0.f;
#pragma unroll
  for (int j = 0; j < 8; ++j) {
    int f = lane + j * 64;
    float hv = bf2f(hw[(size_t)n * HID + f]);
    acc0 += hv * wp0[f];
    acc1 += hv * wp1[f];
  }
#pragma unroll
  for (int off = 32; off; off >>= 1) {
    acc0 += __shfl_down(acc0, off, 64);
    acc1 += __shfl_down(acc1, off, 64);
  }
  if (lane == 0) {
    float l0 = acc0 + bp[0], l1 = acc1 + bp[1];
    slog[n * 2] = l0;
    slog[n * 2 + 1] = l1;
    float m = fmaxf(l0, l1);
    float e0 = expf(l0 - m), e1 = expf(l1 - m);
    float inv = 1.f / (e0 + e1);
    s[n * 2] = e0 * inv;
    s[n * 2 + 1] = e1 * inv;
  }
}

// ---------------------------------------------------------------------------
// Kernel E: out_adj_raw[b,i,j] = sum_e w_e * s[src,i] * s[dst,j]
// + mincut_den[b] = sum_e w_e * (s0[src]^2 + s1[src]^2)
// ---------------------------------------------------------------------------
__global__ __launch_bounds__(256) void edge_pass2(
    const int* __restrict__ src, const int* __restrict__ dst,
    const float* __restrict__ ew, const float* __restrict__ s,
    float* __restrict__ oadj, float* __restrict__ mden) {
  int b = blockIdx.x >> 6;
  int sub = blockIdx.x & 63;
  int base = b * EE + sub * 1024;
  float p00 = 0, p01 = 0, p10 = 0, p11 = 0, md = 0;
  for (int i = threadIdx.x; i < 1024; i += 256) {
    int e = base + i;
    int r = src[e], c = dst[e];
    float w = ew[e];
    float s0r = s[r * 2], s1r = s[r * 2 + 1];
    float s0c = s[c * 2], s1c = s[c * 2 + 1];
    p00 += w * s0r * s0c; p01 += w * s0r * s1c;
    p10 += w * s1r * s0c; p11 += w * s1r * s1c;
    md  += w * (s0r * s0r + s1r * s1r);
  }
#pragma unroll
  for (int off = 32; off; off >>= 1) {
    p00 += __shfl_down(p00, off, 64);
    p01 += __shfl_down(p01, off, 64);
    p10 += __shfl_down(p10, off, 64);
    p11 += __shfl_down(p11, off, 64);
    md  += __shfl_down(md,  off, 64);
  }
  __shared__ float red[4][5];
  int wave = threadIdx.x >> 6, lane = threadIdx.x & 63;
  if (lane == 0) {
    red[wave][0] = p00; red[wave][1] = p01;
    red[wave][2] = p10; red[wave][3] = p11;
    red[wave][4] = md;
  }
  __syncthreads();
  if (threadIdx.x < 4) {
    float v = red[0][threadIdx.x] + red[1][threadIdx.x] +
              red[2][threadIdx.x] + red[3][threadIdx.x];
    atomicAdd(&oadj[b * 4 + threadIdx.x], v);
  } else if (threadIdx.x == 4) {
    float v = red[0][4] + red[1][4] + red[2][4] + red[3][4];
    atomicAdd(&mden[b], v);
  }
}

// ---------------------------------------------------------------------------
// Kernel F: out[b,c,:] += s[n,c]*h[n,:] ; ss accumulators
// ---------------------------------------------------------------------------
__global__ __launch_bounds__(256) void node_acc(
    const ushort* __restrict__ hw, const float* __restrict__ s,
    float* __restrict__ outp, float* __restrict__ ssacc) {
  int blk = blockIdx.x;            // 128 blocks
  int b = blk >> 4;
  int n0 = blk * 256;
  int t = threadIdx.x;
  float a00 = 0, a01 = 0, a10 = 0, a11 = 0;
  float sa = 0, sb = 0, scv = 0;
  for (int i = 0; i < 256; ++i) {
    int n = n0 + i;
    float s0 = s[n * 2], s1 = s[n * 2 + 1];
    float h0 = bf2f(hw[(size_t)n * HID + t]);
    float h1 = bf2f(hw[(size_t)n * HID + t + 256]);
    a00 += s0 * h0; a01 += s0 * h1;
    a10 += s1 * h0; a11 += s1 * h1;
    if (t == 0) {
      sa += s0 * s0; sb += s0 * s1; scv += s1 * s1;
    }
  }
  atomicAdd(&outp[b * 1024 + t], a00);
  atomicAdd(&outp[b * 1024 + t + 256], a01);
  atomicAdd(&outp[b * 1024 + 512 + t], a10);
  atomicAdd(&outp[b * 1024 + 512 + t + 256], a11);
  if (t == 0) {
    atomicAdd(&ssacc[b * 4 + 0], sa);
    atomicAdd(&ssacc[b * 4 + 1], sb);
    atomicAdd(&ssacc[b * 4 + 2], scv);
  }
}

// ---------------------------------------------------------------------------
// Kernel G1: per-graph scalars + build u,v vectors.
// ---------------------------------------------------------------------------
__global__ __launch_bounds__(256) void finalize_a(
    const float* __restrict__ outp, const float* __restrict__ oadj,
    const float* __restrict__ ssacc, const float* __restrict__ mden,
    float* __restrict__ uv, float* __restrict__ dout) {
  __shared__ float sc[2];
  int b = blockIdx.x, t = threadIdx.x;
  if (t == 0) {
    float r00 = oadj[b * 4 + 0], r01 = oadj[b * 4 + 1];
    float r10 = oadj[b * 4 + 2], r11 = oadj[b * 4 + 3];
    atomicAdd(&dout[80], -((r00 + r11) / mden[b]) / (float)BB);
    float a = ssacc[b * 4 + 0], bb = ssacc[b * 4 + 1], c = ssacc[b * 4 + 2];
    float nrm = sqrtf(a * a + 2.f * bb * bb + c * c);
    float q = 0.70710678118654752f;
    float da = a / nrm - q, db = bb / nrm, dc = c / nrm - q;
    atomicAdd(&dout[81], sqrtf(da * da + 2.f * db * db + dc * dc) / (float)BB);
    float d20 = sqrtf(r01) + 1e-15f;
    float d21 = sqrtf(r10) + 1e-15f;
    float oa01 = r01 / (d20 * d21);
    float oa10 = r10 / (d21 * d20);
    dout[65618 + b * 4 + 0] = 0.f;
    dout[65618 + b * 4 + 1] = oa01;
    dout[65618 + b * 4 + 2] = oa10;
    dout[65618 + b * 4 + 3] = 0.f;
    sc[0] = oa01; sc[1] = oa10;
  }
  __syncthreads();
  float oa01 = sc[0], oa10 = sc[1];
  for (int f = t; f < HID; f += 256) {
    float o0 = outp[b * 1024 + f];
    float o1 = outp[b * 1024 + 512 + f];
    uv[b * HID + f] = oa10 * o1 + oa01 * o0;           // u
    uv[BB * HID + b * HID + f] = o0 + o1;              // v
  }
}

// ---------------------------------------------------------------------------
// Kernel G2: conv3 split-K partials. Grid 128 = kc(16) x fc(8).
// ---------------------------------------------------------------------------
__global__ __launch_bounds__(256) void conv3_part(
    const float* __restrict__ uv, const float* __restrict__ Wrel3,
    const float* __restrict__ Wroot3, float* __restrict__ xmacc) {
  __shared__ float us[8][32], vs[8][32];
  __shared__ float red[4][64][8];
  int blk = blockIdx.x;
  int fc = blk & 7, kc = blk >> 3;
  int t = threadIdx.x;
  {
    int b = t >> 5, k = t & 31;
    us[b][k] = uv[b * HID + kc * 32 + k];
    vs[b][k] = uv[BB * HID + b * HID + kc * 32 + k];
  }
  __syncthreads();
  int f = fc * 64 + (t & 63);
  int ks = t >> 6;                 // 0..3
  float acc[8] = {0, 0, 0, 0, 0, 0, 0, 0};
#pragma unroll
  for (int j = 0; j < 8; ++j) {
    int kl = ks * 8 + j;           // 0..31
    int k = kc * 32 + kl;
    float wr = Wrel3[k * HID + f];
    float wo = Wroot3[k * HID + f];
#pragma unroll
    for (int b = 0; b < 8; ++b)
      acc[b] += us[b][kl] * wr + vs[b][kl] * wo;
  }
#pragma unroll
  for (int b = 0; b < 8; ++b) red[ks][t & 63][b] = acc[b];
  __syncthreads();
  if (ks == 0) {
    int fl = t & 63;
#pragma unroll
    for (int b = 0; b < 8; ++b) {
      float v = red[0][fl][b] + red[1][fl][b] + red[2][fl][b] + red[3][fl][b];
      atomicAdd(&xmacc[b * HID + f], v);
    }
  }
}

// ---------------------------------------------------------------------------
// Kernel G3: lin1 split-K partials; xm = 0.5*xmacc + brel3 at staging.
// ---------------------------------------------------------------------------
__global__ __launch_bounds__(256) void lin1_part(
    const float* __restrict__ xmacc, const float* __restrict__ brel3,
    const float* __restrict__ Wlin1, float* __restrict__ h2acc) {
  __shared__ float xs[8][32];
  __shared__ float red[4][64][8];
  int blk = blockIdx.x;
  int fc = blk & 7, kc = blk >> 3;
  int t = threadIdx.x;
  {
    int b = t >> 5, k = t & 31;
    xs[b][k] = 0.5f * xmacc[b * HID + kc * 32 + k] + brel3[kc * 32 + k];
  }
  __syncthreads();
  int f = fc * 64 + (t & 63);
  int ks = t >> 6;
  float acc[8] = {0, 0, 0, 0, 0, 0, 0, 0};
#pragma unroll
  for (int j = 0; j < 8; ++j) {
    int kl = ks * 8 + j;
    int k = kc * 32 + kl;
    float w = Wlin1[k * HID + f];
#pragma unroll
    for (int b = 0; b < 8; ++b)
      acc[b] += xs[b][kl] * w;
  }
#pragma unroll
  for (int b = 0; b < 8; ++b) red[ks][t & 63][b] = acc[b];
  __syncthreads();
  if (ks == 0) {
    int fl = t & 63;
#pragma unroll
    for (int b = 0; b < 8; ++b) {
      float v = red[0][fl][b] + red[1][fl][b] + red[2][fl][b] + red[3][fl][b];
      atomicAdd(&h2acc[b * HID + f], v);
    }
  }
}

// ---------------------------------------------------------------------------
// Kernel G4: logits + log_softmax; h2 = relu(h2acc + blin1) at staging.
// ---------------------------------------------------------------------------
__global__ __launch_bounds__(256) void head(
    const float* __restrict__ h2acc, const float* __restrict__ blin1,
    const float* __restrict__ Wlin2, const float* __restrict__ blin2,
    float* __restrict__ dout) {
  __shared__ float hs[HID];
  __shared__ float lg[16];
  __shared__ float lse;
  int b = blockIdx.x, t = threadIdx.x;
  for (int i = t; i < HID; i += 256)
    hs[i] = fmaxf(h2acc[b * HID + i] + blin1[i], 0.f);
  __syncthreads();
  int wave = t >> 6, lane = t & 63;
  for (int o = wave; o < OUTC; o += 4) {
    float acc = 0.f;
    for (int k = lane; k < HID; k += 64)
      acc += hs[k] * Wlin2[k * OUTC + o];
#pragma unroll
    for (int off = 32; off; off >>= 1) acc += __shfl_down(acc, off, 64);
    if (lane == 0) lg[o] = acc + blin2[o];
  }
  __syncthreads();
  if (t == 0) {
    float m = lg[0];
    for (int o = 1; o < OUTC; ++o) m = fmaxf(m, lg[o]);
    float se = 0.f;
    for (int o = 0; o < OUTC; ++o) se += expf(lg[o] - m);
    lse = m + logf(se);
  }
  __syncthreads();
  if (t < OUTC) dout[b * OUTC + t] = lg[t] - lse;
}

// ---------------------------------------------------------------------------
// Launcher
// ---------------------------------------------------------------------------
extern "C" void kernel_launch(void* const* d_in, const int* in_sizes, int n_in,
                              void* d_out, int out_size, void* d_ws, size_t ws_size,
                              hipStream_t stream) {
  const float* x      = (const float*)d_in[0];
  const int*   ei     = (const int*)d_in[1];
  const float* ew     = (const float*)d_in[3];
  const float* Wrel1  = (const float*)d_in[4];
  const float* brel1  = (const float*)d_in[5];
  const float* Wroot1 = (const float*)d_in[6];
  const float* Wpool  = (const float*)d_in[7];
  const float* bpool  = (const float*)d_in[8];
  const float* Wrel3  = (const float*)d_in[9];
  const float* brel3  = (const float*)d_in[10];
  const float* Wroot3 = (const float*)d_in[11];
  const float* Wlin1  = (const float*)d_in[12];
  const float* blin1  = (const float*)d_in[13];
  const float* Wlin2  = (const float*)d_in[14];
  const float* blin2  = (const float*)d_in[15];
  float* out = (float*)d_out;
  float* ws  = (float*)d_ws;

  // workspace layout (float units)
  float* outp  = ws + 32768;                // [32768, 40960)
  float* oadj  = outp + 8192;               // [40960, 40992)
  float* ssacc = oadj + 32;                 // [40992, 41024)
  float* mden  = ssacc + 32;                // [41024, 41032)  zero-region end
  float* uv    = ws + 41032;                // 8192  [41032, 49224)
  ushort* Ab   = (ushort*)(ws + 106568);    // 32768x256 bf16  [106568, 4300872)
  ushort* Bb   = (ushort*)(ws + 4300872);   // 512x256 bf16    [4300872, 4366408)
  ushort* hbf  = (ushort*)(ws + 4366408);   // 32768x512 bf16  [4366408, 12755016)
  float* xmacc = ws + 12755016;             // 4096
  float* h2acc = xmacc + 4096;              // 4096
  // alias: s overlays Ab (Ab dead after gemm)
  float* s     = ws + 106568;

  const int* src = ei;
  const int* dst = ei + BE;

  hipMemsetAsync(outp, 0, (size_t)8264 * sizeof(float), stream);
  hipMemsetAsync(xmacc, 0, (size_t)8192 * sizeof(float), stream);
  hipMemsetAsync(out + 80, 2 * sizeof(float) ? 0 : 0, 2 * sizeof(float), stream);

  fused_agg  <<<512, 256, 0, stream>>>(src, dst, ew, x, Ab);
  cast_x     <<<4096, 256, 0, stream>>>(x, Ab);
  cast_w     <<<512, 256, 0, stream>>>(Wrel1, Wroot1, Bb);
  gemm_mfma  <<<1024, 256, 0, stream>>>(Ab, Bb, brel1, hbf);
  pool_softmax<<<BN / 4, 256, 0, stream>>>(hbf, Wpool, bpool, s, out + 82);
  edge_pass2 <<<BB * 64, 256, 0, stream>>>(src, dst, ew, s, oadj, mden);
  node_acc   <<<BN / 256, 256, 0, stream>>>(hbf, s, outp, ssacc);
  finalize_a <<<BB, 256, 0, stream>>>(outp, oadj, ssacc, mden, uv, out);
  conv3_part <<<128, 256, 0, stream>>>(uv, Wrel3, Wroot3, xmacc);
  lin1_part  <<<128, 256, 0, stream>>>(xmacc, brel3, Wlin1, h2acc);
  head       <<<BB, 256, 0, stream>>>(h2acc, blin1, Wlin2, blin2, out);
}

// Round 8
// 310.871 us; speedup vs baseline: 1.8545x; 1.8545x over previous
//
#include <hip/hip_runtime.h>
#include <hip/hip_bf16.h>

// Problem constants
#define BB 8
#define NN 4096
#define EE 65536            // edges per graph
#define BE (BB*EE)          // 524288 total edges
#define BN (BB*NN)          // 32768 total nodes
#define INF 128
#define HID 512
#define CC 2
#define OUTC 10

typedef __bf16 bf16x8_t __attribute__((ext_vector_type(8)));
typedef float  f32x4_t  __attribute__((ext_vector_type(4)));

__device__ __forceinline__ ushort f2bf(float f) {
  union { float f; unsigned u; } v; v.f = f;
  unsigned r = v.u + 0x7FFFu + ((v.u >> 16) & 1u);   // RNE
  return (ushort)(r >> 16);
}
__device__ __forceinline__ float bf2f(ushort s) {
  union { unsigned u; float f; } v; v.u = ((unsigned)s) << 16;
  return v.f;
}

// ---------------------------------------------------------------------------
// Kernel A1: owner-computes degree histogram. 512 blocks = (graph b = blk&7,
// dst-range r = blk>>3, 64 nodes). Scans only the dst stream (int4); LDS int
// histogram; plain stores. Zero global atomics. blk&7 keeps each graph's dst
// on one XCD's L2 (64 reader blocks per graph).
// ---------------------------------------------------------------------------
__global__ __launch_bounds__(256) void edge_count(
    const int* __restrict__ dst, int* __restrict__ deg) {
  __shared__ int cnt[64];
  int blk = blockIdx.x;
  int b = blk & 7, r = blk >> 3;
  int nbase = b * NN + r * 64;
  int t = threadIdx.x;
  if (t < 64) cnt[t] = 0;
  __syncthreads();
  const int4* d4 = (const int4*)(dst + (size_t)b * EE);
  for (int i = t; i < EE / 4; i += 256) {
    int4 v = d4[i];
    int a;
    a = v.x - nbase; if ((unsigned)a < 64u) atomicAdd(&cnt[a], 1);
    a = v.y - nbase; if ((unsigned)a < 64u) atomicAdd(&cnt[a], 1);
    a = v.z - nbase; if ((unsigned)a < 64u) atomicAdd(&cnt[a], 1);
    a = v.w - nbase; if ((unsigned)a < 64u) atomicAdd(&cnt[a], 1);
  }
  __syncthreads();
  if (t < 64) deg[nbase + t] = cnt[t];
}

// ---------------------------------------------------------------------------
// Kernel A2: exclusive prefix sum of deg[0..32767] -> off (pristine starts).
// ---------------------------------------------------------------------------
__global__ __launch_bounds__(1024) void scan_kernel(
    const int* __restrict__ deg, int* __restrict__ off) {
  __shared__ int part[1024];
  int t = threadIdx.x;
  int local[32];
  int s = 0;
#pragma unroll
  for (int i = 0; i < 32; ++i) { local[i] = s; s += deg[t * 32 + i]; }
  part[t] = s;
  __syncthreads();
  for (int o = 1; o < 1024; o <<= 1) {
    int v = (t >= o) ? part[t - o] : 0;
    __syncthreads();
    part[t] += v;
    __syncthreads();
  }
  int base = (t == 0) ? 0 : part[t - 1];
#pragma unroll
  for (int i = 0; i < 32; ++i) off[t * 32 + i] = base + local[i];
}

// ---------------------------------------------------------------------------
// Kernel A3: owner-computes bucketing, 512 blocks (64 dsts each). Streams the
// dst array; loads src/ew ONLY for owned hits (~1024/block, ~6% of iters).
// 64 LDS int cursors seeded from off; writes land in exclusively-owned CSR
// ranges (scan is node-ordered). Zero global atomics.
// ---------------------------------------------------------------------------
__global__ __launch_bounds__(256) void edge_bucket(
    const int* __restrict__ src, const int* __restrict__ dst,
    const float* __restrict__ ew, const int* __restrict__ off,
    int* __restrict__ ebs, float* __restrict__ ebw) {
  __shared__ int cur[64];
  int blk = blockIdx.x;
  int b = blk & 7, r = blk >> 3;
  int nbase = b * NN + r * 64;
  int t = threadIdx.x;
  if (t < 64) cur[t] = off[nbase + t];
  __syncthreads();
  size_t e0 = (size_t)b * EE;
  const int4* d4 = (const int4*)(dst + e0);
  for (int i = t; i < EE / 4; i += 256) {
    int4 dv = d4[i];
    int e = i * 4;
    int a;
    a = dv.x - nbase; if ((unsigned)a < 64u) { int p = atomicAdd(&cur[a], 1); ebs[p] = src[e0 + e + 0]; ebw[p] = ew[e0 + e + 0]; }
    a = dv.y - nbase; if ((unsigned)a < 64u) { int p = atomicAdd(&cur[a], 1); ebs[p] = src[e0 + e + 1]; ebw[p] = ew[e0 + e + 1]; }
    a = dv.z - nbase; if ((unsigned)a < 64u) { int p = atomicAdd(&cur[a], 1); ebs[p] = src[e0 + e + 2]; ebw[p] = ew[e0 + e + 2]; }
    a = dv.w - nbase; if ((unsigned)a < 64u) { int p = atomicAdd(&cur[a], 1); ebs[p] = src[e0 + e + 3]; ebw[p] = ew[e0 + e + 3]; }
  }
}

// ---------------------------------------------------------------------------
// Kernel A4: gather  A[n, 0:128] = bf16( sum_{e: dst=n} w_e * x[src_e,:] )
// ---------------------------------------------------------------------------
__global__ __launch_bounds__(256) void gather_agg(
    const int* __restrict__ off, const int* __restrict__ deg,
    const int* __restrict__ ebs, const float* __restrict__ ebw,
    const float* __restrict__ x, ushort* __restrict__ Ab) {
  int n = blockIdx.x * 4 + (threadIdx.x >> 6);
  int lane = threadIdx.x & 63;
  int beg = off[n];
  int end = beg + deg[n];
  float ax = 0.f, ay = 0.f;
  int i = beg;
  for (; i + 1 < end; i += 2) {
    int s0 = ebs[i], s1 = ebs[i + 1];
    float w0 = ebw[i], w1 = ebw[i + 1];
    float2 v0 = *(const float2*)&x[(size_t)s0 * INF + lane * 2];
    float2 v1 = *(const float2*)&x[(size_t)s1 * INF + lane * 2];
    ax += w0 * v0.x + w1 * v1.x;
    ay += w0 * v0.y + w1 * v1.y;
  }
  if (i < end) {
    int s0 = ebs[i];
    float w0 = ebw[i];
    float2 v0 = *(const float2*)&x[(size_t)s0 * INF + lane * 2];
    ax += w0 * v0.x;
    ay += w0 * v0.y;
  }
  ushort2 o; o.x = f2bf(ax); o.y = f2bf(ay);
  *(ushort2*)&Ab[(size_t)n * 256 + lane * 2] = o;
}

// ---------------------------------------------------------------------------
// Kernel A5: cast x -> A[:, 128:256] bf16.  One float4 per thread.
// ---------------------------------------------------------------------------
__global__ __launch_bounds__(256) void cast_x(
    const float* __restrict__ x, ushort* __restrict__ Ab) {
  int g = blockIdx.x * 256 + threadIdx.x;        // 0..1048575
  float4 v = *(const float4*)&x[(size_t)g * 4];
  int m = g >> 5;
  int kin = (g & 31) * 4;
  ushort4 o;
  o.x = f2bf(v.x); o.y = f2bf(v.y); o.z = f2bf(v.z); o.w = f2bf(v.w);
  *(ushort4*)&Ab[(size_t)m * 256 + 128 + kin] = o;
}

// ---------------------------------------------------------------------------
// Kernel A6: Bb[n][k] = bf16 of [Wrel1;Wroot1][k][n]  (pre-transposed weights)
// ---------------------------------------------------------------------------
__global__ __launch_bounds__(256) void cast_w(
    const float* __restrict__ Wrel, const float* __restrict__ Wroot,
    ushort* __restrict__ Bb) {
  int g = blockIdx.x * 256 + threadIdx.x;        // 0..131071
  int n = g & 511, k = g >> 9;
  float w = (k < 128) ? Wrel[k * 512 + n] : Wroot[(k - 128) * 512 + n];
  Bb[n * 256 + k] = f2bf(w);
}

// ---------------------------------------------------------------------------
// Kernel C: MFMA GEMM  h = relu(A(32768x256) @ B(256x512) + b), bf16 in/out.
// 128x128 tile, 4 waves, 16x16x32 bf16 MFMA, BK=32, XCD-swizzled grid.
// ---------------------------------------------------------------------------
#define LDA 40
__global__ __launch_bounds__(256) void gemm_mfma(
    const ushort* __restrict__ Ab, const ushort* __restrict__ Bb,
    const float* __restrict__ brel, ushort* __restrict__ hw) {
  __shared__ ushort As[128 * LDA];
  __shared__ ushort Bs[128 * LDA];
  int tid = threadIdx.x;
  int blk = blockIdx.x;
  int xcd = blk & 7;
  int idx = blk >> 3;              // 0..127
  int by = xcd * 32 + (idx & 31);  // 0..255
  int bx = idx >> 5;               // 0..3
  int m0 = by * 128, n0 = bx * 128;
  int wave = tid >> 6, lane = tid & 63;
  int wm = (wave >> 1) * 64, wn = (wave & 1) * 64;
  int l16 = lane & 15, quad = lane >> 4;

  f32x4_t acc[4][4];
#pragma unroll
  for (int i = 0; i < 4; ++i)
#pragma unroll
    for (int j = 0; j < 4; ++j) acc[i][j] = (f32x4_t){0.f, 0.f, 0.f, 0.f};

  int r0 = tid >> 2,          k0 = (tid & 3) * 8;
  int r1 = (tid + 256) >> 2,  k1 = (tid & 3) * 8;

  int aoff[4], boff[4];
#pragma unroll
  for (int i = 0; i < 4; ++i) {
    aoff[i] = (wm + i * 16 + l16) * LDA + quad * 8;
    boff[i] = (wn + i * 16 + l16) * LDA + quad * 8;
  }

  for (int kc = 0; kc < 256; kc += 32) {
    *(uint4*)&As[r0 * LDA + k0] = *(const uint4*)&Ab[(size_t)(m0 + r0) * 256 + kc + k0];
    *(uint4*)&As[r1 * LDA + k1] = *(const uint4*)&Ab[(size_t)(m0 + r1) * 256 + kc + k1];
    *(uint4*)&Bs[r0 * LDA + k0] = *(const uint4*)&Bb[(size_t)(n0 + r0) * 256 + kc + k0];
    *(uint4*)&Bs[r1 * LDA + k1] = *(const uint4*)&Bb[(size_t)(n0 + r1) * 256 + kc + k1];
    __syncthreads();
    bf16x8_t af[4], bf[4];
#pragma unroll
    for (int i = 0; i < 4; ++i) {
      af[i] = *(const bf16x8_t*)&As[aoff[i]];
      bf[i] = *(const bf16x8_t*)&Bs[boff[i]];
    }
#pragma unroll
    for (int mt = 0; mt < 4; ++mt)
#pragma unroll
      for (int nt = 0; nt < 4; ++nt)
        acc[mt][nt] = __builtin_amdgcn_mfma_f32_16x16x32_bf16(af[mt], bf[nt], acc[mt][nt], 0, 0, 0);
    __syncthreads();
  }

#pragma unroll
  for (int nt = 0; nt < 4; ++nt) {
    int col = n0 + wn + nt * 16 + l16;
    float bias = brel[col];
#pragma unroll
    for (int mt = 0; mt < 4; ++mt) {
      int rowb = m0 + wm + mt * 16 + quad * 4;
#pragma unroll
      for (int r = 0; r < 4; ++r) {
        float v = fmaxf(acc[mt][nt][r] + bias, 0.f);
        hw[(size_t)(rowb + r) * 512 + col] = f2bf(v);
      }
    }
  }
}

// ---------------------------------------------------------------------------
// Kernel D: s_logits = h @ W_pool + b_pool ; s = softmax(s_logits). h is bf16.
// ---------------------------------------------------------------------------
__global__ __launch_bounds__(256) void pool_softmax(
    const ushort* __restrict__ hw, const float* __restrict__ Wp,
    const float* __restrict__ bp, float* __restrict__ s,
    float* __restrict__ slog) {
  __shared__ float wp0[HID], wp1[HID];
  int tid = threadIdx.x;
  for (int i = tid; i < HID; i += 256) {
    wp0[i] = Wp[i * 2];
    wp1[i] = Wp[i * 2 + 1];
  }
  __syncthreads();
  int wave = tid >> 6, lane = tid & 63;
  int n = blockIdx.x * 4 + wave;
  float acc0 = 0.f, acc1 = 0.f;
#pragma unroll
  for (int j = 0; j < 8; ++j) {
    int f = lane + j * 64;
    float hv = bf2f(hw[(size_t)n * HID + f]);
    acc0 += hv * wp0[f];
    acc1 += hv * wp1[f];
  }
#pragma unroll
  for (int off = 32; off; off >>= 1) {
    acc0 += __shfl_down(acc0, off, 64);
    acc1 += __shfl_down(acc1, off, 64);
  }
  if (lane == 0) {
    float l0 = acc0 + bp[0], l1 = acc1 + bp[1];
    slog[n * 2] = l0;
    slog[n * 2 + 1] = l1;
    float m = fmaxf(l0, l1);
    float e0 = expf(l0 - m), e1 = expf(l1 - m);
    float inv = 1.f / (e0 + e1);
    s[n * 2] = e0 * inv;
    s[n * 2 + 1] = e1 * inv;
  }
}

// ---------------------------------------------------------------------------
// Kernel E: out_adj_raw[b,i,j] = sum_e w_e * s[src,i] * s[dst,j]
// + mincut_den[b] = sum_e w_e * (s0[src]^2 + s1[src]^2)
// ---------------------------------------------------------------------------
__global__ __launch_bounds__(256) void edge_pass2(
    const int* __restrict__ src, const int* __restrict__ dst,
    const float* __restrict__ ew, const float* __restrict__ s,
    float* __restrict__ oadj, float* __restrict__ mden) {
  int b = blockIdx.x >> 6;
  int sub = blockIdx.x & 63;
  int base = b * EE + sub * 1024;
  float p00 = 0, p01 = 0, p10 = 0, p11 = 0, md = 0;
  for (int i = threadIdx.x; i < 1024; i += 256) {
    int e = base + i;
    int r = src[e], c = dst[e];
    float w = ew[e];
    float s0r = s[r * 2], s1r = s[r * 2 + 1];
    float s0c = s[c * 2], s1c = s[c * 2 + 1];
    p00 += w * s0r * s0c; p01 += w * s0r * s1c;
    p10 += w * s1r * s0c; p11 += w * s1r * s1c;
    md  += w * (s0r * s0r + s1r * s1r);
  }
#pragma unroll
  for (int off = 32; off; off >>= 1) {
    p00 += __shfl_down(p00, off, 64);
    p01 += __shfl_down(p01, off, 64);
    p10 += __shfl_down(p10, off, 64);
    p11 += __shfl_down(p11, off, 64);
    md  += __shfl_down(md,  off, 64);
  }
  __shared__ float red[4][5];
  int wave = threadIdx.x >> 6, lane = threadIdx.x & 63;
  if (lane == 0) {
    red[wave][0] = p00; red[wave][1] = p01;
    red[wave][2] = p10; red[wave][3] = p11;
    red[wave][4] = md;
  }
  __syncthreads();
  if (threadIdx.x < 4) {
    float v = red[0][threadIdx.x] + red[1][threadIdx.x] +
              red[2][threadIdx.x] + red[3][threadIdx.x];
    atomicAdd(&oadj[b * 4 + threadIdx.x], v);
  } else if (threadIdx.x == 4) {
    float v = red[0][4] + red[1][4] + red[2][4] + red[3][4];
    atomicAdd(&mden[b], v);
  }
}

// ---------------------------------------------------------------------------
// Kernel F: out[b,c,:] += s[n,c]*h[n,:] ; ss accumulators
// ---------------------------------------------------------------------------
__global__ __launch_bounds__(256) void node_acc(
    const ushort* __restrict__ hw, const float* __restrict__ s,
    float* __restrict__ outp, float* __restrict__ ssacc) {
  int blk = blockIdx.x;            // 128 blocks
  int b = blk >> 4;
  int n0 = blk * 256;
  int t = threadIdx.x;
  float a00 = 0, a01 = 0, a10 = 0, a11 = 0;
  float sa = 0, sb = 0, scv = 0;
  for (int i = 0; i < 256; ++i) {
    int n = n0 + i;
    float s0 = s[n * 2], s1 = s[n * 2 + 1];
    float h0 = bf2f(hw[(size_t)n * HID + t]);
    float h1 = bf2f(hw[(size_t)n * HID + t + 256]);
    a00 += s0 * h0; a01 += s0 * h1;
    a10 += s1 * h0; a11 += s1 * h1;
    if (t == 0) {
      sa += s0 * s0; sb += s0 * s1; scv += s1 * s1;
    }
  }
  atomicAdd(&outp[b * 1024 + t], a00);
  atomicAdd(&outp[b * 1024 + t + 256], a01);
  atomicAdd(&outp[b * 1024 + 512 + t], a10);
  atomicAdd(&outp[b * 1024 + 512 + t + 256], a11);
  if (t == 0) {
    atomicAdd(&ssacc[b * 4 + 0], sa);
    atomicAdd(&ssacc[b * 4 + 1], sb);
    atomicAdd(&ssacc[b * 4 + 2], scv);
  }
}

// ---------------------------------------------------------------------------
// Kernel G1: per-graph scalars + build u,v vectors.
// ---------------------------------------------------------------------------
__global__ __launch_bounds__(256) void finalize_a(
    const float* __restrict__ outp, const float* __restrict__ oadj,
    const float* __restrict__ ssacc, const float* __restrict__ mden,
    float* __restrict__ uv, float* __restrict__ dout) {
  __shared__ float sc[2];
  int b = blockIdx.x, t = threadIdx.x;
  if (t == 0) {
    float r00 = oadj[b * 4 + 0], r01 = oadj[b * 4 + 1];
    float r10 = oadj[b * 4 + 2], r11 = oadj[b * 4 + 3];
    atomicAdd(&dout[80], -((r00 + r11) / mden[b]) / (float)BB);
    float a = ssacc[b * 4 + 0], bb = ssacc[b * 4 + 1], c = ssacc[b * 4 + 2];
    float nrm = sqrtf(a * a + 2.f * bb * bb + c * c);
    float q = 0.70710678118654752f;
    float da = a / nrm - q, db = bb / nrm, dc = c / nrm - q;
    atomicAdd(&dout[81], sqrtf(da * da + 2.f * db * db + dc * dc) / (float)BB);
    float d20 = sqrtf(r01) + 1e-15f;
    float d21 = sqrtf(r10) + 1e-15f;
    float oa01 = r01 / (d20 * d21);
    float oa10 = r10 / (d21 * d20);
    dout[65618 + b * 4 + 0] = 0.f;
    dout[65618 + b * 4 + 1] = oa01;
    dout[65618 + b * 4 + 2] = oa10;
    dout[65618 + b * 4 + 3] = 0.f;
    sc[0] = oa01; sc[1] = oa10;
  }
  __syncthreads();
  float oa01 = sc[0], oa10 = sc[1];
  for (int f = t; f < HID; f += 256) {
    float o0 = outp[b * 1024 + f];
    float o1 = outp[b * 1024 + 512 + f];
    uv[b * HID + f] = oa10 * o1 + oa01 * o0;           // u
    uv[BB * HID + b * HID + f] = o0 + o1;              // v
  }
}

// ---------------------------------------------------------------------------
// Kernel G2: conv3 split-K partials. Grid 128 = kc(16) x fc(8).
// ---------------------------------------------------------------------------
__global__ __launch_bounds__(256) void conv3_part(
    const float* __restrict__ uv, const float* __restrict__ Wrel3,
    const float* __restrict__ Wroot3, float* __restrict__ xmacc) {
  __shared__ float us[8][32], vs[8][32];
  __shared__ float red[4][64][8];
  int blk = blockIdx.x;
  int fc = blk & 7, kc = blk >> 3;
  int t = threadIdx.x;
  {
    int b = t >> 5, k = t & 31;
    us[b][k] = uv[b * HID + kc * 32 + k];
    vs[b][k] = uv[BB * HID + b * HID + kc * 32 + k];
  }
  __syncthreads();
  int f = fc * 64 + (t & 63);
  int ks = t >> 6;                 // 0..3
  float acc[8] = {0, 0, 0, 0, 0, 0, 0, 0};
#pragma unroll
  for (int j = 0; j < 8; ++j) {
    int kl = ks * 8 + j;           // 0..31
    int k = kc * 32 + kl;
    float wr = Wrel3[k * HID + f];
    float wo = Wroot3[k * HID + f];
#pragma unroll
    for (int b = 0; b < 8; ++b)
      acc[b] += us[b][kl] * wr + vs[b][kl] * wo;
  }
#pragma unroll
  for (int b = 0; b < 8; ++b) red[ks][t & 63][b] = acc[b];
  __syncthreads();
  if (ks == 0) {
    int fl = t & 63;
#pragma unroll
    for (int b = 0; b < 8; ++b) {
      float v = red[0][fl][b] + red[1][fl][b] + red[2][fl][b] + red[3][fl][b];
      atomicAdd(&xmacc[b * HID + f], v);
    }
  }
}

// ---------------------------------------------------------------------------
// Kernel G3: lin1 split-K partials; xm = 0.5*xmacc + brel3 at staging.
// ---------------------------------------------------------------------------
__global__ __launch_bounds__(256) void lin1_part(
    const float* __restrict__ xmacc, const float* __restrict__ brel3,
    const float* __restrict__ Wlin1, float* __restrict__ h2acc) {
  __shared__ float xs[8][32];
  __shared__ float red[4][64][8];
  int blk = blockIdx.x;
  int fc = blk & 7, kc = blk >> 3;
  int t = threadIdx.x;
  {
    int b = t >> 5, k = t & 31;
    xs[b][k] = 0.5f * xmacc[b * HID + kc * 32 + k] + brel3[kc * 32 + k];
  }
  __syncthreads();
  int f = fc * 64 + (t & 63);
  int ks = t >> 6;
  float acc[8] = {0, 0, 0, 0, 0, 0, 0, 0};
#pragma unroll
  for (int j = 0; j < 8; ++j) {
    int kl = ks * 8 + j;
    int k = kc * 32 + kl;
    float w = Wlin1[k * HID + f];
#pragma unroll
    for (int b = 0; b < 8; ++b)
      acc[b] += xs[b][kl] * w;
  }
#pragma unroll
  for (int b = 0; b < 8; ++b) red[ks][t & 63][b] = acc[b];
  __syncthreads();
  if (ks == 0) {
    int fl = t & 63;
#pragma unroll
    for (int b = 0; b < 8; ++b) {
      float v = red[0][fl][b] + red[1][fl][b] + red[2][fl][b] + red[3][fl][b];
      atomicAdd(&h2acc[b * HID + f], v);
    }
  }
}

// ---------------------------------------------------------------------------
// Kernel G4: logits + log_softmax; h2 = relu(h2acc + blin1) at staging.
// ---------------------------------------------------------------------------
__global__ __launch_bounds__(256) void head(
    const float* __restrict__ h2acc, const float* __restrict__ blin1,
    const float* __restrict__ Wlin2, const float* __restrict__ blin2,
    float* __restrict__ dout) {
  __shared__ float hs[HID];
  __shared__ float lg[16];
  __shared__ float lse;
  int b = blockIdx.x, t = threadIdx.x;
  for (int i = t; i < HID; i += 256)
    hs[i] = fmaxf(h2acc[b * HID + i] + blin1[i], 0.f);
  __syncthreads();
  int wave = t >> 6, lane = t & 63;
  for (int o = wave; o < OUTC; o += 4) {
    float acc = 0.f;
    for (int k = lane; k < HID; k += 64)
      acc += hs[k] * Wlin2[k * OUTC + o];
#pragma unroll
    for (int off = 32; off; off >>= 1) acc += __shfl_down(acc, off, 64);
    if (lane == 0) lg[o] = acc + blin2[o];
  }
  __syncthreads();
  if (t == 0) {
    float m = lg[0];
    for (int o = 1; o < OUTC; ++o) m = fmaxf(m, lg[o]);
    float se = 0.f;
    for (int o = 0; o < OUTC; ++o) se += expf(lg[o] - m);
    lse = m + logf(se);
  }
  __syncthreads();
  if (t < OUTC) dout[b * OUTC + t] = lg[t] - lse;
}

// ---------------------------------------------------------------------------
// Launcher
// ---------------------------------------------------------------------------
extern "C" void kernel_launch(void* const* d_in, const int* in_sizes, int n_in,
                              void* d_out, int out_size, void* d_ws, size_t ws_size,
                              hipStream_t stream) {
  const float* x      = (const float*)d_in[0];
  const int*   ei     = (const int*)d_in[1];
  const float* ew     = (const float*)d_in[3];
  const float* Wrel1  = (const float*)d_in[4];
  const float* brel1  = (const float*)d_in[5];
  const float* Wroot1 = (const float*)d_in[6];
  const float* Wpool  = (const float*)d_in[7];
  const float* bpool  = (const float*)d_in[8];
  const float* Wrel3  = (const float*)d_in[9];
  const float* brel3  = (const float*)d_in[10];
  const float* Wroot3 = (const float*)d_in[11];
  const float* Wlin1  = (const float*)d_in[12];
  const float* blin1  = (const float*)d_in[13];
  const float* Wlin2  = (const float*)d_in[14];
  const float* blin2  = (const float*)d_in[15];
  float* out = (float*)d_out;
  float* ws  = (float*)d_ws;

  // workspace layout (float units)
  float* outp  = ws + 32768;                // [32768, 40960)
  float* oadj  = outp + 8192;               // [40960, 40992)
  float* ssacc = oadj + 32;                 // [40992, 41024)
  float* mden  = ssacc + 32;                // [41024, 41032)  zero-region end
  int*   deg   = (int*)(mden + 8);          // [41032, 73800)
  int*   off   = deg + 32768;               // [73800, 106568)
  ushort* Ab   = (ushort*)(ws + 106568);    // 32768x256 bf16  [106568, 4300872)
  ushort* Bb   = (ushort*)(ws + 4300872);   // 512x256 bf16    [4300872, 4366408)
  ushort* hbf  = (ushort*)(ws + 4366408);   // 32768x512 bf16  [4366408, 12755016)
  float* xmacc = ws + 12755016;             // 4096
  float* h2acc = xmacc + 4096;              // 4096
  // aliases (lifetimes by stream order):
  int*   ebs   = (int*)(ws + 4366408);      // inside h region; dead before gemm writes h
  float* ebw   = ws + 4890696;              // inside h region
  float* s     = ws + 106568;               // overlays Ab; Ab dead after gemm
  float* uv    = (float*)deg;               // deg dead after gather_agg

  const int* src = ei;
  const int* dst = ei + BE;

  hipMemsetAsync(outp, 0, (size_t)8264 * sizeof(float), stream);
  hipMemsetAsync(xmacc, 0, (size_t)8192 * sizeof(float), stream);
  hipMemsetAsync(out + 80, 0, 2 * sizeof(float), stream);

  edge_count <<<512, 256, 0, stream>>>(dst, deg);
  scan_kernel<<<1, 1024, 0, stream>>>(deg, off);
  edge_bucket<<<512, 256, 0, stream>>>(src, dst, ew, off, ebs, ebw);
  gather_agg <<<BN / 4, 256, 0, stream>>>(off, deg, ebs, ebw, x, Ab);
  cast_x     <<<4096, 256, 0, stream>>>(x, Ab);
  cast_w     <<<512, 256, 0, stream>>>(Wrel1, Wroot1, Bb);
  gemm_mfma  <<<1024, 256, 0, stream>>>(Ab, Bb, brel1, hbf);
  pool_softmax<<<BN / 4, 256, 0, stream>>>(hbf, Wpool, bpool, s, out + 82);
  edge_pass2 <<<BB * 64, 256, 0, stream>>>(src, dst, ew, s, oadj, mden);
  node_acc   <<<BN / 256, 256, 0, stream>>>(hbf, s, outp, ssacc);
  finalize_a <<<BB, 256, 0, stream>>>(outp, oadj, ssacc, mden, uv, out);
  conv3_part <<<128, 256, 0, stream>>>(uv, Wrel3, Wroot3, xmacc);
  lin1_part  <<<128, 256, 0, stream>>>(xmacc, brel3, Wlin1, h2acc);
  head       <<<BB, 256, 0, stream>>>(h2acc, blin1, Wlin2, blin2, out);
}

// Round 9
// 260.363 us; speedup vs baseline: 2.2142x; 1.1940x over previous
//
#include <hip/hip_runtime.h>
#include <hip/hip_bf16.h>

// Problem constants
#define BB 8
#define NN 4096
#define EE 65536            // edges per graph
#define BE (BB*EE)          // 524288 total edges
#define BN (BB*NN)          // 32768 total nodes
#define INF 128
#define HID 512
#define CC 2
#define OUTC 10
#define ELLCAP 64           // max in-degree capacity (Binomial mean 16, P(>=64)<1e-13)

typedef __bf16 bf16x8_t __attribute__((ext_vector_type(8)));
typedef float  f32x4_t  __attribute__((ext_vector_type(4)));

__device__ __forceinline__ ushort f2bf(float f) {
  union { float f; unsigned u; } v; v.f = f;
  unsigned r = v.u + 0x7FFFu + ((v.u >> 16) & 1u);   // RNE
  return (ushort)(r >> 16);
}
__device__ __forceinline__ float bf2f(ushort s) {
  union { unsigned u; float f; } v; v.u = ((unsigned)s) << 16;
  return v.f;
}

// ---------------------------------------------------------------------------
// Kernel A1: ELL build. One global atomic per edge claims a slot in dst's
// fixed-capacity row. Replaces count+scan+bucket (the CSR) entirely.
// ---------------------------------------------------------------------------
__global__ __launch_bounds__(256) void ell_build(
    const int* __restrict__ src, const int* __restrict__ dst,
    const float* __restrict__ ew, int* __restrict__ deg,
    int* __restrict__ ebs, float* __restrict__ ebw) {
  int e = blockIdx.x * 256 + threadIdx.x;
  if (e >= BE) return;
  int d = dst[e];
  int p = atomicAdd(&deg[d], 1);
  if (p < ELLCAP) {
    ebs[(size_t)d * ELLCAP + p] = src[e];
    ebw[(size_t)d * ELLCAP + p] = ew[e];
  }
}

// ---------------------------------------------------------------------------
// Kernel A5: cast x -> A[:, 128:256] bf16.  One float4 per thread.
// (Must run BEFORE gather_ell: gather reads this bf16 copy of x.)
// ---------------------------------------------------------------------------
__global__ __launch_bounds__(256) void cast_x(
    const float* __restrict__ x, ushort* __restrict__ Ab) {
  int g = blockIdx.x * 256 + threadIdx.x;        // 0..1048575
  float4 v = *(const float4*)&x[(size_t)g * 4];
  int m = g >> 5;
  int kin = (g & 31) * 4;
  ushort4 o;
  o.x = f2bf(v.x); o.y = f2bf(v.y); o.z = f2bf(v.z); o.w = f2bf(v.w);
  *(ushort4*)&Ab[(size_t)m * 256 + 128 + kin] = o;
}

// ---------------------------------------------------------------------------
// Kernel A4: gather  A[n, 0:128] = bf16( sum_j w_j * xbf16[src_j,:] )
// one wave per node; lane owns 2 feats; reads the bf16 x at Ab[:,128:256]
// (half the bytes of fp32 x; L2/L3-resident).
// ---------------------------------------------------------------------------
__global__ __launch_bounds__(256) void gather_ell(
    const int* __restrict__ deg, const int* __restrict__ ebs,
    const float* __restrict__ ebw, ushort* __restrict__ Ab) {
  int n = blockIdx.x * 4 + (threadIdx.x >> 6);
  int lane = threadIdx.x & 63;
  int d = deg[n]; if (d > ELLCAP) d = ELLCAP;
  const int*   es = ebs + (size_t)n * ELLCAP;
  const float* wsr = ebw + (size_t)n * ELLCAP;
  float ax = 0.f, ay = 0.f;
  int j = 0;
  for (; j + 1 < d; j += 2) {
    int s0 = es[j], s1 = es[j + 1];
    float w0 = wsr[j], w1 = wsr[j + 1];
    ushort2 u0 = *(const ushort2*)&Ab[(size_t)s0 * 256 + 128 + lane * 2];
    ushort2 u1 = *(const ushort2*)&Ab[(size_t)s1 * 256 + 128 + lane * 2];
    ax += w0 * bf2f(u0.x) + w1 * bf2f(u1.x);
    ay += w0 * bf2f(u0.y) + w1 * bf2f(u1.y);
  }
  if (j < d) {
    int s0 = es[j];
    float w0 = wsr[j];
    ushort2 u0 = *(const ushort2*)&Ab[(size_t)s0 * 256 + 128 + lane * 2];
    ax += w0 * bf2f(u0.x);
    ay += w0 * bf2f(u0.y);
  }
  ushort2 o; o.x = f2bf(ax); o.y = f2bf(ay);
  *(ushort2*)&Ab[(size_t)n * 256 + lane * 2] = o;
}

// ---------------------------------------------------------------------------
// Kernel A6: Bb[n][k] = bf16 of [Wrel1;Wroot1][k][n]  (pre-transposed weights)
// ---------------------------------------------------------------------------
__global__ __launch_bounds__(256) void cast_w(
    const float* __restrict__ Wrel, const float* __restrict__ Wroot,
    ushort* __restrict__ Bb) {
  int g = blockIdx.x * 256 + threadIdx.x;        // 0..131071
  int n = g & 511, k = g >> 9;
  float w = (k < 128) ? Wrel[k * 512 + n] : Wroot[(k - 128) * 512 + n];
  Bb[n * 256 + k] = f2bf(w);
}

// ---------------------------------------------------------------------------
// Kernel C: MFMA GEMM  h = relu(A(32768x256) @ B(256x512) + b), bf16 in/out.
// 128x128 tile, 4 waves, 16x16x32 bf16 MFMA, BK=32, XCD-swizzled grid.
// ---------------------------------------------------------------------------
#define LDA 40
__global__ __launch_bounds__(256) void gemm_mfma(
    const ushort* __restrict__ Ab, const ushort* __restrict__ Bb,
    const float* __restrict__ brel, ushort* __restrict__ hw) {
  __shared__ ushort As[128 * LDA];
  __shared__ ushort Bs[128 * LDA];
  int tid = threadIdx.x;
  int blk = blockIdx.x;
  int xcd = blk & 7;
  int idx = blk >> 3;              // 0..127
  int by = xcd * 32 + (idx & 31);  // 0..255
  int bx = idx >> 5;               // 0..3
  int m0 = by * 128, n0 = bx * 128;
  int wave = tid >> 6, lane = tid & 63;
  int wm = (wave >> 1) * 64, wn = (wave & 1) * 64;
  int l16 = lane & 15, quad = lane >> 4;

  f32x4_t acc[4][4];
#pragma unroll
  for (int i = 0; i < 4; ++i)
#pragma unroll
    for (int j = 0; j < 4; ++j) acc[i][j] = (f32x4_t){0.f, 0.f, 0.f, 0.f};

  int r0 = tid >> 2,          k0 = (tid & 3) * 8;
  int r1 = (tid + 256) >> 2,  k1 = (tid & 3) * 8;

  int aoff[4], boff[4];
#pragma unroll
  for (int i = 0; i < 4; ++i) {
    aoff[i] = (wm + i * 16 + l16) * LDA + quad * 8;
    boff[i] = (wn + i * 16 + l16) * LDA + quad * 8;
  }

  for (int kc = 0; kc < 256; kc += 32) {
    *(uint4*)&As[r0 * LDA + k0] = *(const uint4*)&Ab[(size_t)(m0 + r0) * 256 + kc + k0];
    *(uint4*)&As[r1 * LDA + k1] = *(const uint4*)&Ab[(size_t)(m0 + r1) * 256 + kc + k1];
    *(uint4*)&Bs[r0 * LDA + k0] = *(const uint4*)&Bb[(size_t)(n0 + r0) * 256 + kc + k0];
    *(uint4*)&Bs[r1 * LDA + k1] = *(const uint4*)&Bb[(size_t)(n0 + r1) * 256 + kc + k1];
    __syncthreads();
    bf16x8_t af[4], bf[4];
#pragma unroll
    for (int i = 0; i < 4; ++i) {
      af[i] = *(const bf16x8_t*)&As[aoff[i]];
      bf[i] = *(const bf16x8_t*)&Bs[boff[i]];
    }
#pragma unroll
    for (int mt = 0; mt < 4; ++mt)
#pragma unroll
      for (int nt = 0; nt < 4; ++nt)
        acc[mt][nt] = __builtin_amdgcn_mfma_f32_16x16x32_bf16(af[mt], bf[nt], acc[mt][nt], 0, 0, 0);
    __syncthreads();
  }

#pragma unroll
  for (int nt = 0; nt < 4; ++nt) {
    int col = n0 + wn + nt * 16 + l16;
    float bias = brel[col];
#pragma unroll
    for (int mt = 0; mt < 4; ++mt) {
      int rowb = m0 + wm + mt * 16 + quad * 4;
#pragma unroll
      for (int r = 0; r < 4; ++r) {
        float v = fmaxf(acc[mt][nt][r] + bias, 0.f);
        hw[(size_t)(rowb + r) * 512 + col] = f2bf(v);
      }
    }
  }
}

// ---------------------------------------------------------------------------
// Kernel D: s_logits = h @ W_pool + b_pool ; s = softmax(s_logits). h is bf16.
// ---------------------------------------------------------------------------
__global__ __launch_bounds__(256) void pool_softmax(
    const ushort* __restrict__ hw, const float* __restrict__ Wp,
    const float* __restrict__ bp, float* __restrict__ s,
    float* __restrict__ slog) {
  __shared__ float wp0[HID], wp1[HID];
  int tid = threadIdx.x;
  for (int i = tid; i < HID; i += 256) {
    wp0[i] = Wp[i * 2];
    wp1[i] = Wp[i * 2 + 1];
  }
  __syncthreads();
  int wave = tid >> 6, lane = tid & 63;
  int n = blockIdx.x * 4 + wave;
  float acc0 = 0.f, acc1 = 0.f;
#pragma unroll
  for (int j = 0; j < 8; ++j) {
    int f = lane + j * 64;
    float hv = bf2f(hw[(size_t)n * HID + f]);
    acc0 += hv * wp0[f];
    acc1 += hv * wp1[f];
  }
#pragma unroll
  for (int off = 32; off; off >>= 1) {
    acc0 += __shfl_down(acc0, off, 64);
    acc1 += __shfl_down(acc1, off, 64);
  }
  if (lane == 0) {
    float l0 = acc0 + bp[0], l1 = acc1 + bp[1];
    slog[n * 2] = l0;
    slog[n * 2 + 1] = l1;
    float m = fmaxf(l0, l1);
    float e0 = expf(l0 - m), e1 = expf(l1 - m);
    float inv = 1.f / (e0 + e1);
    s[n * 2] = e0 * inv;
    s[n * 2 + 1] = e1 * inv;
  }
}

// ---------------------------------------------------------------------------
// Kernel E: out_adj_raw[b,i,j] = sum_e w_e * s[src,i] * s[dst,j]
// + mincut_den[b] = sum_e w_e * (s0[src]^2 + s1[src]^2)
// ---------------------------------------------------------------------------
__global__ __launch_bounds__(256) void edge_pass2(
    const int* __restrict__ src, const int* __restrict__ dst,
    const float* __restrict__ ew, const float* __restrict__ s,
    float* __restrict__ oadj, float* __restrict__ mden) {
  int b = blockIdx.x >> 6;
  int sub = blockIdx.x & 63;
  int base = b * EE + sub * 1024;
  float p00 = 0, p01 = 0, p10 = 0, p11 = 0, md = 0;
  for (int i = threadIdx.x; i < 1024; i += 256) {
    int e = base + i;
    int r = src[e], c = dst[e];
    float w = ew[e];
    float s0r = s[r * 2], s1r = s[r * 2 + 1];
    float s0c = s[c * 2], s1c = s[c * 2 + 1];
    p00 += w * s0r * s0c; p01 += w * s0r * s1c;
    p10 += w * s1r * s0c; p11 += w * s1r * s1c;
    md  += w * (s0r * s0r + s1r * s1r);
  }
#pragma unroll
  for (int off = 32; off; off >>= 1) {
    p00 += __shfl_down(p00, off, 64);
    p01 += __shfl_down(p01, off, 64);
    p10 += __shfl_down(p10, off, 64);
    p11 += __shfl_down(p11, off, 64);
    md  += __shfl_down(md,  off, 64);
  }
  __shared__ float red[4][5];
  int wave = threadIdx.x >> 6, lane = threadIdx.x & 63;
  if (lane == 0) {
    red[wave][0] = p00; red[wave][1] = p01;
    red[wave][2] = p10; red[wave][3] = p11;
    red[wave][4] = md;
  }
  __syncthreads();
  if (threadIdx.x < 4) {
    float v = red[0][threadIdx.x] + red[1][threadIdx.x] +
              red[2][threadIdx.x] + red[3][threadIdx.x];
    atomicAdd(&oadj[b * 4 + threadIdx.x], v);
  } else if (threadIdx.x == 4) {
    float v = red[0][4] + red[1][4] + red[2][4] + red[3][4];
    atomicAdd(&mden[b], v);
  }
}

// ---------------------------------------------------------------------------
// Kernel F: out[b,c,:] += s[n,c]*h[n,:] ; ss accumulators
// ---------------------------------------------------------------------------
__global__ __launch_bounds__(256) void node_acc(
    const ushort* __restrict__ hw, const float* __restrict__ s,
    float* __restrict__ outp, float* __restrict__ ssacc) {
  int blk = blockIdx.x;            // 128 blocks
  int b = blk >> 4;
  int n0 = blk * 256;
  int t = threadIdx.x;
  float a00 = 0, a01 = 0, a10 = 0, a11 = 0;
  float sa = 0, sb = 0, scv = 0;
  for (int i = 0; i < 256; ++i) {
    int n = n0 + i;
    float s0 = s[n * 2], s1 = s[n * 2 + 1];
    float h0 = bf2f(hw[(size_t)n * HID + t]);
    float h1 = bf2f(hw[(size_t)n * HID + t + 256]);
    a00 += s0 * h0; a01 += s0 * h1;
    a10 += s1 * h0; a11 += s1 * h1;
    if (t == 0) {
      sa += s0 * s0; sb += s0 * s1; scv += s1 * s1;
    }
  }
  atomicAdd(&outp[b * 1024 + t], a00);
  atomicAdd(&outp[b * 1024 + t + 256], a01);
  atomicAdd(&outp[b * 1024 + 512 + t], a10);
  atomicAdd(&outp[b * 1024 + 512 + t + 256], a11);
  if (t == 0) {
    atomicAdd(&ssacc[b * 4 + 0], sa);
    atomicAdd(&ssacc[b * 4 + 1], sb);
    atomicAdd(&ssacc[b * 4 + 2], scv);
  }
}

// ---------------------------------------------------------------------------
// Kernel G1: per-graph scalars + build u,v vectors.
// ---------------------------------------------------------------------------
__global__ __launch_bounds__(256) void finalize_a(
    const float* __restrict__ outp, const float* __restrict__ oadj,
    const float* __restrict__ ssacc, const float* __restrict__ mden,
    float* __restrict__ uv, float* __restrict__ dout) {
  __shared__ float sc[2];
  int b = blockIdx.x, t = threadIdx.x;
  if (t == 0) {
    float r00 = oadj[b * 4 + 0], r01 = oadj[b * 4 + 1];
    float r10 = oadj[b * 4 + 2], r11 = oadj[b * 4 + 3];
    atomicAdd(&dout[80], -((r00 + r11) / mden[b]) / (float)BB);
    float a = ssacc[b * 4 + 0], bb = ssacc[b * 4 + 1], c = ssacc[b * 4 + 2];
    float nrm = sqrtf(a * a + 2.f * bb * bb + c * c);
    float q = 0.70710678118654752f;
    float da = a / nrm - q, db = bb / nrm, dc = c / nrm - q;
    atomicAdd(&dout[81], sqrtf(da * da + 2.f * db * db + dc * dc) / (float)BB);
    float d20 = sqrtf(r01) + 1e-15f;
    float d21 = sqrtf(r10) + 1e-15f;
    float oa01 = r01 / (d20 * d21);
    float oa10 = r10 / (d21 * d20);
    dout[65618 + b * 4 + 0] = 0.f;
    dout[65618 + b * 4 + 1] = oa01;
    dout[65618 + b * 4 + 2] = oa10;
    dout[65618 + b * 4 + 3] = 0.f;
    sc[0] = oa01; sc[1] = oa10;
  }
  __syncthreads();
  float oa01 = sc[0], oa10 = sc[1];
  for (int f = t; f < HID; f += 256) {
    float o0 = outp[b * 1024 + f];
    float o1 = outp[b * 1024 + 512 + f];
    uv[b * HID + f] = oa10 * o1 + oa01 * o0;           // u
    uv[BB * HID + b * HID + f] = o0 + o1;              // v
  }
}

// ---------------------------------------------------------------------------
// Kernel G2: conv3 split-K partials. Grid 128 = kc(16) x fc(8).
// ---------------------------------------------------------------------------
__global__ __launch_bounds__(256) void conv3_part(
    const float* __restrict__ uv, const float* __restrict__ Wrel3,
    const float* __restrict__ Wroot3, float* __restrict__ xmacc) {
  __shared__ float us[8][32], vs[8][32];
  __shared__ float red[4][64][8];
  int blk = blockIdx.x;
  int fc = blk & 7, kc = blk >> 3;
  int t = threadIdx.x;
  {
    int b = t >> 5, k = t & 31;
    us[b][k] = uv[b * HID + kc * 32 + k];
    vs[b][k] = uv[BB * HID + b * HID + kc * 32 + k];
  }
  __syncthreads();
  int f = fc * 64 + (t & 63);
  int ks = t >> 6;                 // 0..3
  float acc[8] = {0, 0, 0, 0, 0, 0, 0, 0};
#pragma unroll
  for (int j = 0; j < 8; ++j) {
    int kl = ks * 8 + j;           // 0..31
    int k = kc * 32 + kl;
    float wr = Wrel3[k * HID + f];
    float wo = Wroot3[k * HID + f];
#pragma unroll
    for (int b = 0; b < 8; ++b)
      acc[b] += us[b][kl] * wr + vs[b][kl] * wo;
  }
#pragma unroll
  for (int b = 0; b < 8; ++b) red[ks][t & 63][b] = acc[b];
  __syncthreads();
  if (ks == 0) {
    int fl = t & 63;
#pragma unroll
    for (int b = 0; b < 8; ++b) {
      float v = red[0][fl][b] + red[1][fl][b] + red[2][fl][b] + red[3][fl][b];
      atomicAdd(&xmacc[b * HID + f], v);
    }
  }
}

// ---------------------------------------------------------------------------
// Kernel G3: lin1 split-K partials; xm = 0.5*xmacc + brel3 at staging.
// ---------------------------------------------------------------------------
__global__ __launch_bounds__(256) void lin1_part(
    const float* __restrict__ xmacc, const float* __restrict__ brel3,
    const float* __restrict__ Wlin1, float* __restrict__ h2acc) {
  __shared__ float xs[8][32];
  __shared__ float red[4][64][8];
  int blk = blockIdx.x;
  int fc = blk & 7, kc = blk >> 3;
  int t = threadIdx.x;
  {
    int b = t >> 5, k = t & 31;
    xs[b][k] = 0.5f * xmacc[b * HID + kc * 32 + k] + brel3[kc * 32 + k];
  }
  __syncthreads();
  int f = fc * 64 + (t & 63);
  int ks = t >> 6;
  float acc[8] = {0, 0, 0, 0, 0, 0, 0, 0};
#pragma unroll
  for (int j = 0; j < 8; ++j) {
    int kl = ks * 8 + j;
    int k = kc * 32 + kl;
    float w = Wlin1[k * HID + f];
#pragma unroll
    for (int b = 0; b < 8; ++b)
      acc[b] += xs[b][kl] * w;
  }
#pragma unroll
  for (int b = 0; b < 8; ++b) red[ks][t & 63][b] = acc[b];
  __syncthreads();
  if (ks == 0) {
    int fl = t & 63;
#pragma unroll
    for (int b = 0; b < 8; ++b) {
      float v = red[0][fl][b] + red[1][fl][b] + red[2][fl][b] + red[3][fl][b];
      atomicAdd(&h2acc[b * HID + f], v);
    }
  }
}

// ---------------------------------------------------------------------------
// Kernel G4: logits + log_softmax; h2 = relu(h2acc + blin1) at staging.
// ---------------------------------------------------------------------------
__global__ __launch_bounds__(256) void head(
    const float* __restrict__ h2acc, const float* __restrict__ blin1,
    const float* __restrict__ Wlin2, const float* __restrict__ blin2,
    float* __restrict__ dout) {
  __shared__ float hs[HID];
  __shared__ float lg[16];
  __shared__ float lse;
  int b = blockIdx.x, t = threadIdx.x;
  for (int i = t; i < HID; i += 256)
    hs[i] = fmaxf(h2acc[b * HID + i] + blin1[i], 0.f);
  __syncthreads();
  int wave = t >> 6, lane = t & 63;
  for (int o = wave; o < OUTC; o += 4) {
    float acc = 0.f;
    for (int k = lane; k < HID; k += 64)
      acc += hs[k] * Wlin2[k * OUTC + o];
#pragma unroll
    for (int off = 32; off; off >>= 1) acc += __shfl_down(acc, off, 64);
    if (lane == 0) lg[o] = acc + blin2[o];
  }
  __syncthreads();
  if (t == 0) {
    float m = lg[0];
    for (int o = 1; o < OUTC; ++o) m = fmaxf(m, lg[o]);
    float se = 0.f;
    for (int o = 0; o < OUTC; ++o) se += expf(lg[o] - m);
    lse = m + logf(se);
  }
  __syncthreads();
  if (t < OUTC) dout[b * OUTC + t] = lg[t] - lse;
}

// ---------------------------------------------------------------------------
// Launcher
// ---------------------------------------------------------------------------
extern "C" void kernel_launch(void* const* d_in, const int* in_sizes, int n_in,
                              void* d_out, int out_size, void* d_ws, size_t ws_size,
                              hipStream_t stream) {
  const float* x      = (const float*)d_in[0];
  const int*   ei     = (const int*)d_in[1];
  const float* ew     = (const float*)d_in[3];
  const float* Wrel1  = (const float*)d_in[4];
  const float* brel1  = (const float*)d_in[5];
  const float* Wroot1 = (const float*)d_in[6];
  const float* Wpool  = (const float*)d_in[7];
  const float* bpool  = (const float*)d_in[8];
  const float* Wrel3  = (const float*)d_in[9];
  const float* brel3  = (const float*)d_in[10];
  const float* Wroot3 = (const float*)d_in[11];
  const float* Wlin1  = (const float*)d_in[12];
  const float* blin1  = (const float*)d_in[13];
  const float* Wlin2  = (const float*)d_in[14];
  const float* blin2  = (const float*)d_in[15];
  float* out = (float*)d_out;
  float* ws  = (float*)d_ws;

  // workspace layout (float units)
  float* outp  = ws + 32768;                // [32768, 40960)
  float* oadj  = outp + 8192;               // [40960, 40992)
  float* ssacc = oadj + 32;                 // [40992, 41024)
  float* mden  = ssacc + 32;                // [41024, 41032)
  int*   deg   = (int*)(mden + 8);          // [41032, 73800)  zero-region end
  ushort* Ab   = (ushort*)(ws + 106568);    // 32768x256 bf16  [106568, 4300872)
  ushort* Bb   = (ushort*)(ws + 4300872);   // 512x256 bf16    [4300872, 4366408)
  ushort* hbf  = (ushort*)(ws + 4366408);   // 32768x512 bf16  [4366408, 12755016)
  float* xmacc = ws + 12755016;             // 4096
  float* h2acc = xmacc + 4096;              // 4096
  // aliases (lifetimes by stream order):
  int*   ebs   = (int*)(ws + 4366408);      // 32768*64 ints (8.4MB), inside h region
  float* ebw   = ws + 4366408 + 2097152;    // 32768*64 floats — both dead before gemm writes h
  float* s     = ws + 106568;               // overlays Ab; Ab dead after gemm
  float* uv    = (float*)deg;               // deg dead after gather_ell

  const int* src = ei;
  const int* dst = ei + BE;

  // zero outp/oadj/ssacc/mden/deg (contiguous: 8264 + 32768 floats)
  hipMemsetAsync(outp, 0, (size_t)41032 * sizeof(float), stream);
  hipMemsetAsync(xmacc, 0, (size_t)8192 * sizeof(float), stream);
  hipMemsetAsync(out + 80, 0, 2 * sizeof(float), stream);

  ell_build  <<<BE / 256, 256, 0, stream>>>(src, dst, ew, deg, ebs, ebw);
  cast_x     <<<4096, 256, 0, stream>>>(x, Ab);
  cast_w     <<<512, 256, 0, stream>>>(Wrel1, Wroot1, Bb);
  gather_ell <<<BN / 4, 256, 0, stream>>>(deg, ebs, ebw, Ab);
  gemm_mfma  <<<1024, 256, 0, stream>>>(Ab, Bb, brel1, hbf);
  pool_softmax<<<BN / 4, 256, 0, stream>>>(hbf, Wpool, bpool, s, out + 82);
  edge_pass2 <<<BB * 64, 256, 0, stream>>>(src, dst, ew, s, oadj, mden);
  node_acc   <<<BN / 256, 256, 0, stream>>>(hbf, s, outp, ssacc);
  finalize_a <<<BB, 256, 0, stream>>>(outp, oadj, ssacc, mden, uv, out);
  conv3_part <<<128, 256, 0, stream>>>(uv, Wrel3, Wroot3, xmacc);
  lin1_part  <<<128, 256, 0, stream>>>(xmacc, brel3, Wlin1, h2acc);
  head       <<<BB, 256, 0, stream>>>(h2acc, blin1, Wlin2, blin2, out);
}

// Round 10
// 250.514 us; speedup vs baseline: 2.3013x; 1.0393x over previous
//
#include <hip/hip_runtime.h>
#include <hip/hip_bf16.h>

// Problem constants
#define BB 8
#define NN 4096
#define EE 65536            // edges per graph
#define BE (BB*EE)          // 524288 total edges
#define BN (BB*NN)          // 32768 total nodes
#define INF 128
#define HID 512
#define CC 2
#define OUTC 10
#define ELLCAP 64           // max in-degree capacity (Binomial mean 16, P(>=64)<1e-13)

typedef __bf16 bf16x8_t __attribute__((ext_vector_type(8)));
typedef float  f32x4_t  __attribute__((ext_vector_type(4)));

__device__ __forceinline__ ushort f2bf(float f) {
  union { float f; unsigned u; } v; v.f = f;
  unsigned r = v.u + 0x7FFFu + ((v.u >> 16) & 1u);   // RNE
  return (ushort)(r >> 16);
}
__device__ __forceinline__ float bf2f(ushort s) {
  union { unsigned u; float f; } v; v.u = ((unsigned)s) << 16;
  return v.f;
}

// ---------------------------------------------------------------------------
// Kernel A1: ELL build. One global atomic per edge claims a slot in dst's
// fixed-capacity row.
// ---------------------------------------------------------------------------
__global__ __launch_bounds__(256) void ell_build(
    const int* __restrict__ src, const int* __restrict__ dst,
    const float* __restrict__ ew, int* __restrict__ deg,
    int* __restrict__ ebs, float* __restrict__ ebw) {
  int e = blockIdx.x * 256 + threadIdx.x;
  if (e >= BE) return;
  int d = dst[e];
  int p = atomicAdd(&deg[d], 1);
  if (p < ELLCAP) {
    ebs[(size_t)d * ELLCAP + p] = src[e];
    ebw[(size_t)d * ELLCAP + p] = ew[e];
  }
}

// ---------------------------------------------------------------------------
// Kernel A5: cast x -> A[:, 128:256] bf16 (runs BEFORE gather_ell).
// ---------------------------------------------------------------------------
__global__ __launch_bounds__(256) void cast_x(
    const float* __restrict__ x, ushort* __restrict__ Ab) {
  int g = blockIdx.x * 256 + threadIdx.x;        // 0..1048575
  float4 v = *(const float4*)&x[(size_t)g * 4];
  int m = g >> 5;
  int kin = (g & 31) * 4;
  ushort4 o;
  o.x = f2bf(v.x); o.y = f2bf(v.y); o.z = f2bf(v.z); o.w = f2bf(v.w);
  *(ushort4*)&Ab[(size_t)m * 256 + 128 + kin] = o;
}

// ---------------------------------------------------------------------------
// Kernel A4: gather  A[n, 0:128] = bf16( sum_j w_j * xbf16[src_j,:] )
// ---------------------------------------------------------------------------
__global__ __launch_bounds__(256) void gather_ell(
    const int* __restrict__ deg, const int* __restrict__ ebs,
    const float* __restrict__ ebw, ushort* __restrict__ Ab) {
  int n = blockIdx.x * 4 + (threadIdx.x >> 6);
  int lane = threadIdx.x & 63;
  int d = deg[n]; if (d > ELLCAP) d = ELLCAP;
  const int*   es = ebs + (size_t)n * ELLCAP;
  const float* wsr = ebw + (size_t)n * ELLCAP;
  float ax = 0.f, ay = 0.f;
  int j = 0;
  for (; j + 1 < d; j += 2) {
    int s0 = es[j], s1 = es[j + 1];
    float w0 = wsr[j], w1 = wsr[j + 1];
    ushort2 u0 = *(const ushort2*)&Ab[(size_t)s0 * 256 + 128 + lane * 2];
    ushort2 u1 = *(const ushort2*)&Ab[(size_t)s1 * 256 + 128 + lane * 2];
    ax += w0 * bf2f(u0.x) + w1 * bf2f(u1.x);
    ay += w0 * bf2f(u0.y) + w1 * bf2f(u1.y);
  }
  if (j < d) {
    int s0 = es[j];
    float w0 = wsr[j];
    ushort2 u0 = *(const ushort2*)&Ab[(size_t)s0 * 256 + 128 + lane * 2];
    ax += w0 * bf2f(u0.x);
    ay += w0 * bf2f(u0.y);
  }
  ushort2 o; o.x = f2bf(ax); o.y = f2bf(ay);
  *(ushort2*)&Ab[(size_t)n * 256 + lane * 2] = o;
}

// ---------------------------------------------------------------------------
// Kernel A6: Bb[n][k] = bf16 of [Wrel1;Wroot1][k][n]  (pre-transposed weights)
// ---------------------------------------------------------------------------
__global__ __launch_bounds__(256) void cast_w(
    const float* __restrict__ Wrel, const float* __restrict__ Wroot,
    ushort* __restrict__ Bb) {
  int g = blockIdx.x * 256 + threadIdx.x;        // 0..131071
  int n = g & 511, k = g >> 9;
  float w = (k < 128) ? Wrel[k * 512 + n] : Wroot[(k - 128) * 512 + n];
  Bb[n * 256 + k] = f2bf(w);
}

// ---------------------------------------------------------------------------
// Kernel C: single-stage MFMA GEMM. 64x64 tile, FULL K=256 staged once
// (As/Bs 32 KB each = 64 KB -> 2 blocks/CU), ONE barrier, then 8 k-steps of
// MFMA with no further syncs. XOR-swizzled chunk placement (slot = c^(row&31),
// 16B chunks) makes frag ds_read_b128 2-way bank-aliased (free, m136) without
// padding. Grid 4096, XCD-partitioned: each XCD owns 64 row-tiles x 8
// col-tiles; its 2 MB A-slab stays L2-resident.
// ---------------------------------------------------------------------------
__global__ __launch_bounds__(256) void gemm_mfma(
    const ushort* __restrict__ Ab, const ushort* __restrict__ Bb,
    const float* __restrict__ brel, ushort* __restrict__ hw) {
  __shared__ ushort As[64 * 256];   // 32 KB
  __shared__ ushort Bs[64 * 256];   // 32 KB
  int tid = threadIdx.x;
  int blk = blockIdx.x;
  int xcd = blk & 7;
  int idx = blk >> 3;                  // 0..511
  int by = xcd * 64 + (idx & 63);      // 0..511
  int bx = idx >> 6;                   // 0..7
  int m0 = by * 64, n0 = bx * 64;

  // stage full K: 64 rows x 32 chunks (16B) per array; 8 chunks per thread each
#pragma unroll
  for (int i = 0; i < 8; ++i) {
    int g = tid + i * 256;
    int r = g >> 5, c = g & 31;
    int cs = c ^ (r & 31);
    *(uint4*)&As[(r * 32 + cs) * 8] = *(const uint4*)&Ab[(size_t)(m0 + r) * 256 + c * 8];
    *(uint4*)&Bs[(r * 32 + cs) * 8] = *(const uint4*)&Bb[(size_t)(n0 + r) * 256 + c * 8];
  }
  __syncthreads();

  int wave = tid >> 6, lane = tid & 63;
  int wm = (wave >> 1) * 32, wn = (wave & 1) * 32;
  int l16 = lane & 15, quad = lane >> 4;

  f32x4_t acc[2][2];
#pragma unroll
  for (int f = 0; f < 2; ++f)
#pragma unroll
    for (int g = 0; g < 2; ++g) acc[f][g] = (f32x4_t){0.f, 0.f, 0.f, 0.f};

  int arow[2], brow[2];
#pragma unroll
  for (int f = 0; f < 2; ++f) {
    arow[f] = wm + f * 16 + l16;
    brow[f] = wn + f * 16 + l16;
  }

#pragma unroll
  for (int kc = 0; kc < 8; ++kc) {
    int cl = kc * 4 + quad;            // chunk index of this lane's 8 elems
    bf16x8_t af[2], bf[2];
#pragma unroll
    for (int f = 0; f < 2; ++f) {
      af[f] = *(const bf16x8_t*)&As[(arow[f] * 32 + (cl ^ (arow[f] & 31))) * 8];
      bf[f] = *(const bf16x8_t*)&Bs[(brow[f] * 32 + (cl ^ (brow[f] & 31))) * 8];
    }
#pragma unroll
    for (int f = 0; f < 2; ++f)
#pragma unroll
      for (int g = 0; g < 2; ++g)
        acc[f][g] = __builtin_amdgcn_mfma_f32_16x16x32_bf16(af[f], bf[g], acc[f][g], 0, 0, 0);
  }

#pragma unroll
  for (int g = 0; g < 2; ++g) {
    int col = n0 + wn + g * 16 + l16;
    float bias = brel[col];
#pragma unroll
    for (int f = 0; f < 2; ++f) {
      int rowb = m0 + wm + f * 16 + quad * 4;
#pragma unroll
      for (int r = 0; r < 4; ++r) {
        float v = fmaxf(acc[f][g][r] + bias, 0.f);
        hw[(size_t)(rowb + r) * 512 + col] = f2bf(v);
      }
    }
  }
}

// ---------------------------------------------------------------------------
// Kernel D: s_logits = h @ W_pool + b_pool ; s = softmax(s_logits). h is bf16.
// ---------------------------------------------------------------------------
__global__ __launch_bounds__(256) void pool_softmax(
    const ushort* __restrict__ hw, const float* __restrict__ Wp,
    const float* __restrict__ bp, float* __restrict__ s,
    float* __restrict__ slog) {
  __shared__ float wp0[HID], wp1[HID];
  int tid = threadIdx.x;
  for (int i = tid; i < HID; i += 256) {
    wp0[i] = Wp[i * 2];
    wp1[i] = Wp[i * 2 + 1];
  }
  __syncthreads();
  int wave = tid >> 6, lane = tid & 63;
  int n = blockIdx.x * 4 + wave;
  float acc0 = 0.f, acc1 = 0.f;
#pragma unroll
  for (int j = 0; j < 8; ++j) {
    int f = lane + j * 64;
    float hv = bf2f(hw[(size_t)n * HID + f]);
    acc0 += hv * wp0[f];
    acc1 += hv * wp1[f];
  }
#pragma unroll
  for (int off = 32; off; off >>= 1) {
    acc0 += __shfl_down(acc0, off, 64);
    acc1 += __shfl_down(acc1, off, 64);
  }
  if (lane == 0) {
    float l0 = acc0 + bp[0], l1 = acc1 + bp[1];
    slog[n * 2] = l0;
    slog[n * 2 + 1] = l1;
    float m = fmaxf(l0, l1);
    float e0 = expf(l0 - m), e1 = expf(l1 - m);
    float inv = 1.f / (e0 + e1);
    s[n * 2] = e0 * inv;
    s[n * 2 + 1] = e1 * inv;
  }
}

// ---------------------------------------------------------------------------
// Kernel E: out_adj_raw[b,i,j] = sum_e w_e * s[src,i] * s[dst,j]
// + mincut_den[b] = sum_e w_e * (s0[src]^2 + s1[src]^2)
// ---------------------------------------------------------------------------
__global__ __launch_bounds__(256) void edge_pass2(
    const int* __restrict__ src, const int* __restrict__ dst,
    const float* __restrict__ ew, const float* __restrict__ s,
    float* __restrict__ oadj, float* __restrict__ mden) {
  int b = blockIdx.x >> 6;
  int sub = blockIdx.x & 63;
  int base = b * EE + sub * 1024;
  float p00 = 0, p01 = 0, p10 = 0, p11 = 0, md = 0;
  for (int i = threadIdx.x; i < 1024; i += 256) {
    int e = base + i;
    int r = src[e], c = dst[e];
    float w = ew[e];
    float s0r = s[r * 2], s1r = s[r * 2 + 1];
    float s0c = s[c * 2], s1c = s[c * 2 + 1];
    p00 += w * s0r * s0c; p01 += w * s0r * s1c;
    p10 += w * s1r * s0c; p11 += w * s1r * s1c;
    md  += w * (s0r * s0r + s1r * s1r);
  }
#pragma unroll
  for (int off = 32; off; off >>= 1) {
    p00 += __shfl_down(p00, off, 64);
    p01 += __shfl_down(p01, off, 64);
    p10 += __shfl_down(p10, off, 64);
    p11 += __shfl_down(p11, off, 64);
    md  += __shfl_down(md,  off, 64);
  }
  __shared__ float red[4][5];
  int wave = threadIdx.x >> 6, lane = threadIdx.x & 63;
  if (lane == 0) {
    red[wave][0] = p00; red[wave][1] = p01;
    red[wave][2] = p10; red[wave][3] = p11;
    red[wave][4] = md;
  }
  __syncthreads();
  if (threadIdx.x < 4) {
    float v = red[0][threadIdx.x] + red[1][threadIdx.x] +
              red[2][threadIdx.x] + red[3][threadIdx.x];
    atomicAdd(&oadj[b * 4 + threadIdx.x], v);
  } else if (threadIdx.x == 4) {
    float v = red[0][4] + red[1][4] + red[2][4] + red[3][4];
    atomicAdd(&mden[b], v);
  }
}

// ---------------------------------------------------------------------------
// Kernel F: out[b,c,:] += s[n,c]*h[n,:] ; ss accumulators. 256 blocks
// (128 nodes each) to cover all CUs.
// ---------------------------------------------------------------------------
__global__ __launch_bounds__(256) void node_acc(
    const ushort* __restrict__ hw, const float* __restrict__ s,
    float* __restrict__ outp, float* __restrict__ ssacc) {
  int blk = blockIdx.x;            // 256 blocks
  int b = blk >> 5;                // 32 blocks per graph
  int n0 = blk * 128;
  int t = threadIdx.x;
  float a00 = 0, a01 = 0, a10 = 0, a11 = 0;
  float sa = 0, sb = 0, scv = 0;
  for (int i = 0; i < 128; ++i) {
    int n = n0 + i;
    float s0 = s[n * 2], s1 = s[n * 2 + 1];
    float h0 = bf2f(hw[(size_t)n * HID + t]);
    float h1 = bf2f(hw[(size_t)n * HID + t + 256]);
    a00 += s0 * h0; a01 += s0 * h1;
    a10 += s1 * h0; a11 += s1 * h1;
    if (t == 0) {
      sa += s0 * s0; sb += s0 * s1; scv += s1 * s1;
    }
  }
  atomicAdd(&outp[b * 1024 + t], a00);
  atomicAdd(&outp[b * 1024 + t + 256], a01);
  atomicAdd(&outp[b * 1024 + 512 + t], a10);
  atomicAdd(&outp[b * 1024 + 512 + t + 256], a11);
  if (t == 0) {
    atomicAdd(&ssacc[b * 4 + 0], sa);
    atomicAdd(&ssacc[b * 4 + 1], sb);
    atomicAdd(&ssacc[b * 4 + 2], scv);
  }
}

// ---------------------------------------------------------------------------
// Kernel G1: per-graph scalars + build u,v vectors.
// ---------------------------------------------------------------------------
__global__ __launch_bounds__(256) void finalize_a(
    const float* __restrict__ outp, const float* __restrict__ oadj,
    const float* __restrict__ ssacc, const float* __restrict__ mden,
    float* __restrict__ uv, float* __restrict__ dout) {
  __shared__ float sc[2];
  int b = blockIdx.x, t = threadIdx.x;
  if (t == 0) {
    float r00 = oadj[b * 4 + 0], r01 = oadj[b * 4 + 1];
    float r10 = oadj[b * 4 + 2], r11 = oadj[b * 4 + 3];
    atomicAdd(&dout[80], -((r00 + r11) / mden[b]) / (float)BB);
    float a = ssacc[b * 4 + 0], bb = ssacc[b * 4 + 1], c = ssacc[b * 4 + 2];
    float nrm = sqrtf(a * a + 2.f * bb * bb + c * c);
    float q = 0.70710678118654752f;
    float da = a / nrm - q, db = bb / nrm, dc = c / nrm - q;
    atomicAdd(&dout[81], sqrtf(da * da + 2.f * db * db + dc * dc) / (float)BB);
    float d20 = sqrtf(r01) + 1e-15f;
    float d21 = sqrtf(r10) + 1e-15f;
    float oa01 = r01 / (d20 * d21);
    float oa10 = r10 / (d21 * d20);
    dout[65618 + b * 4 + 0] = 0.f;
    dout[65618 + b * 4 + 1] = oa01;
    dout[65618 + b * 4 + 2] = oa10;
    dout[65618 + b * 4 + 3] = 0.f;
    sc[0] = oa01; sc[1] = oa10;
  }
  __syncthreads();
  float oa01 = sc[0], oa10 = sc[1];
  for (int f = t; f < HID; f += 256) {
    float o0 = outp[b * 1024 + f];
    float o1 = outp[b * 1024 + 512 + f];
    uv[b * HID + f] = oa10 * o1 + oa01 * o0;           // u
    uv[BB * HID + b * HID + f] = o0 + o1;              // v
  }
}

// ---------------------------------------------------------------------------
// Kernel G2: conv3 split-K partials. Grid 128 = kc(16) x fc(8).
// ---------------------------------------------------------------------------
__global__ __launch_bounds__(256) void conv3_part(
    const float* __restrict__ uv, const float* __restrict__ Wrel3,
    const float* __restrict__ Wroot3, float* __restrict__ xmacc) {
  __shared__ float us[8][32], vs[8][32];
  __shared__ float red[4][64][8];
  int blk = blockIdx.x;
  int fc = blk & 7, kc = blk >> 3;
  int t = threadIdx.x;
  {
    int b = t >> 5, k = t & 31;
    us[b][k] = uv[b * HID + kc * 32 + k];
    vs[b][k] = uv[BB * HID + b * HID + kc * 32 + k];
  }
  __syncthreads();
  int f = fc * 64 + (t & 63);
  int ks = t >> 6;                 // 0..3
  float acc[8] = {0, 0, 0, 0, 0, 0, 0, 0};
#pragma unroll
  for (int j = 0; j < 8; ++j) {
    int kl = ks * 8 + j;           // 0..31
    int k = kc * 32 + kl;
    float wr = Wrel3[k * HID + f];
    float wo = Wroot3[k * HID + f];
#pragma unroll
    for (int b = 0; b < 8; ++b)
      acc[b] += us[b][kl] * wr + vs[b][kl] * wo;
  }
#pragma unroll
  for (int b = 0; b < 8; ++b) red[ks][t & 63][b] = acc[b];
  __syncthreads();
  if (ks == 0) {
    int fl = t & 63;
#pragma unroll
    for (int b = 0; b < 8; ++b) {
      float v = red[0][fl][b] + red[1][fl][b] + red[2][fl][b] + red[3][fl][b];
      atomicAdd(&xmacc[b * HID + f], v);
    }
  }
}

// ---------------------------------------------------------------------------
// Kernel G3: lin1 split-K partials; xm = 0.5*xmacc + brel3 at staging.
// ---------------------------------------------------------------------------
__global__ __launch_bounds__(256) void lin1_part(
    const float* __restrict__ xmacc, const float* __restrict__ brel3,
    const float* __restrict__ Wlin1, float* __restrict__ h2acc) {
  __shared__ float xs[8][32];
  __shared__ float red[4][64][8];
  int blk = blockIdx.x;
  int fc = blk & 7, kc = blk >> 3;
  int t = threadIdx.x;
  {
    int b = t >> 5, k = t & 31;
    xs[b][k] = 0.5f * xmacc[b * HID + kc * 32 + k] + brel3[kc * 32 + k];
  }
  __syncthreads();
  int f = fc * 64 + (t & 63);
  int ks = t >> 6;
  float acc[8] = {0, 0, 0, 0, 0, 0, 0, 0};
#pragma unroll
  for (int j = 0; j < 8; ++j) {
    int kl = ks * 8 + j;
    int k = kc * 32 + kl;
    float w = Wlin1[k * HID + f];
#pragma unroll
    for (int b = 0; b < 8; ++b)
      acc[b] += xs[b][kl] * w;
  }
#pragma unroll
  for (int b = 0; b < 8; ++b) red[ks][t & 63][b] = acc[b];
  __syncthreads();
  if (ks == 0) {
    int fl = t & 63;
#pragma unroll
    for (int b = 0; b < 8; ++b) {
      float v = red[0][fl][b] + red[1][fl][b] + red[2][fl][b] + red[3][fl][b];
      atomicAdd(&h2acc[b * HID + f], v);
    }
  }
}

// ---------------------------------------------------------------------------
// Kernel G4: logits + log_softmax; h2 = relu(h2acc + blin1) at staging.
// ---------------------------------------------------------------------------
__global__ __launch_bounds__(256) void head(
    const float* __restrict__ h2acc, const float* __restrict__ blin1,
    const float* __restrict__ Wlin2, const float* __restrict__ blin2,
    float* __restrict__ dout) {
  __shared__ float hs[HID];
  __shared__ float lg[16];
  __shared__ float lse;
  int b = blockIdx.x, t = threadIdx.x;
  for (int i = t; i < HID; i += 256)
    hs[i] = fmaxf(h2acc[b * HID + i] + blin1[i], 0.f);
  __syncthreads();
  int wave = t >> 6, lane = t & 63;
  for (int o = wave; o < OUTC; o += 4) {
    float acc = 0.f;
    for (int k = lane; k < HID; k += 64)
      acc += hs[k] * Wlin2[k * OUTC + o];
#pragma unroll
    for (int off = 32; off; off >>= 1) acc += __shfl_down(acc, off, 64);
    if (lane == 0) lg[o] = acc + blin2[o];
  }
  __syncthreads();
  if (t == 0) {
    float m = lg[0];
    for (int o = 1; o < OUTC; ++o) m = fmaxf(m, lg[o]);
    float se = 0.f;
    for (int o = 0; o < OUTC; ++o) se += expf(lg[o] - m);
    lse = m + logf(se);
  }
  __syncthreads();
  if (t < OUTC) dout[b * OUTC + t] = lg[t] - lse;
}

// ---------------------------------------------------------------------------
// Launcher
// ---------------------------------------------------------------------------
extern "C" void kernel_launch(void* const* d_in, const int* in_sizes, int n_in,
                              void* d_out, int out_size, void* d_ws, size_t ws_size,
                              hipStream_t stream) {
  const float* x      = (const float*)d_in[0];
  const int*   ei     = (const int*)d_in[1];
  const float* ew     = (const float*)d_in[3];
  const float* Wrel1  = (const float*)d_in[4];
  const float* brel1  = (const float*)d_in[5];
  const float* Wroot1 = (const float*)d_in[6];
  const float* Wpool  = (const float*)d_in[7];
  const float* bpool  = (const float*)d_in[8];
  const float* Wrel3  = (const float*)d_in[9];
  const float* brel3  = (const float*)d_in[10];
  const float* Wroot3 = (const float*)d_in[11];
  const float* Wlin1  = (const float*)d_in[12];
  const float* blin1  = (const float*)d_in[13];
  const float* Wlin2  = (const float*)d_in[14];
  const float* blin2  = (const float*)d_in[15];
  float* out = (float*)d_out;
  float* ws  = (float*)d_ws;

  // workspace layout (float units)
  float* outp  = ws + 32768;                // [32768, 40960)
  float* oadj  = outp + 8192;               // [40960, 40992)
  float* ssacc = oadj + 32;                 // [40992, 41024)
  float* mden  = ssacc + 32;                // [41024, 41032)
  int*   deg   = (int*)(mden + 8);          // [41032, 73800)  zero-region end
  ushort* Ab   = (ushort*)(ws + 106568);    // 32768x256 bf16  [106568, 4300872)
  ushort* Bb   = (ushort*)(ws + 4300872);   // 512x256 bf16    [4300872, 4366408)
  ushort* hbf  = (ushort*)(ws + 4366408);   // 32768x512 bf16  [4366408, 12755016)
  float* xmacc = ws + 12755016;             // 4096
  float* h2acc = xmacc + 4096;              // 4096
  // aliases (lifetimes by stream order):
  int*   ebs   = (int*)(ws + 4366408);      // 32768*64 ints (8.4MB), inside h region
  float* ebw   = ws + 4366408 + 2097152;    // 32768*64 floats — both dead before gemm writes h
  float* s     = ws + 106568;               // overlays Ab; Ab dead after gemm
  float* uv    = (float*)deg;               // deg dead after gather_ell

  const int* src = ei;
  const int* dst = ei + BE;

  hipMemsetAsync(outp, 0, (size_t)41032 * sizeof(float), stream);
  hipMemsetAsync(xmacc, 0, (size_t)8192 * sizeof(float), stream);
  hipMemsetAsync(out + 80, 0, 2 * sizeof(float), stream);

  ell_build  <<<BE / 256, 256, 0, stream>>>(src, dst, ew, deg, ebs, ebw);
  cast_x     <<<4096, 256, 0, stream>>>(x, Ab);
  cast_w     <<<512, 256, 0, stream>>>(Wrel1, Wroot1, Bb);
  gather_ell <<<BN / 4, 256, 0, stream>>>(deg, ebs, ebw, Ab);
  gemm_mfma  <<<4096, 256, 0, stream>>>(Ab, Bb, brel1, hbf);
  pool_softmax<<<BN / 4, 256, 0, stream>>>(hbf, Wpool, bpool, s, out + 82);
  edge_pass2 <<<BB * 64, 256, 0, stream>>>(src, dst, ew, s, oadj, mden);
  node_acc   <<<256, 256, 0, stream>>>(hbf, s, outp, ssacc);
  finalize_a <<<BB, 256, 0, stream>>>(outp, oadj, ssacc, mden, uv, out);
  conv3_part <<<128, 256, 0, stream>>>(uv, Wrel3, Wroot3, xmacc);
  lin1_part  <<<128, 256, 0, stream>>>(xmacc, brel3, Wlin1, h2acc);
  head       <<<BB, 256, 0, stream>>>(h2acc, blin1, Wlin2, blin2, out);
}

// Round 11
// 244.510 us; speedup vs baseline: 2.3578x; 1.0246x over previous
//
#include <hip/hip_runtime.h>
#include <hip/hip_bf16.h>

// Problem constants
#define BB 8
#define NN 4096
#define EE 65536            // edges per graph
#define BE (BB*EE)          // 524288 total edges
#define BN (BB*NN)          // 32768 total nodes
#define INF 128
#define HID 512
#define CC 2
#define OUTC 10
#define ELLCAP 64           // max in-degree capacity (Binomial mean 16, P(>=64)<1e-13)

typedef __bf16 bf16x8_t __attribute__((ext_vector_type(8)));
typedef float  f32x4_t  __attribute__((ext_vector_type(4)));

__device__ __forceinline__ ushort f2bf(float f) {
  union { float f; unsigned u; } v; v.f = f;
  unsigned r = v.u + 0x7FFFu + ((v.u >> 16) & 1u);   // RNE
  return (ushort)(r >> 16);
}
__device__ __forceinline__ float bf2f(ushort s) {
  union { unsigned u; float f; } v; v.u = ((unsigned)s) << 16;
  return v.f;
}

// ---------------------------------------------------------------------------
// Kernel A1: ELL build. One global atomic per edge claims a slot in dst's
// fixed-capacity row.
// ---------------------------------------------------------------------------
__global__ __launch_bounds__(256) void ell_build(
    const int* __restrict__ src, const int* __restrict__ dst,
    const float* __restrict__ ew, int* __restrict__ deg,
    int* __restrict__ ebs, float* __restrict__ ebw) {
  int e = blockIdx.x * 256 + threadIdx.x;
  if (e >= BE) return;
  int d = dst[e];
  int p = atomicAdd(&deg[d], 1);
  if (p < ELLCAP) {
    ebs[(size_t)d * ELLCAP + p] = src[e];
    ebw[(size_t)d * ELLCAP + p] = ew[e];
  }
}

// ---------------------------------------------------------------------------
// Kernel A5: cast x -> A[:, 128:256] bf16 (runs BEFORE gather_ell).
// ---------------------------------------------------------------------------
__global__ __launch_bounds__(256) void cast_x(
    const float* __restrict__ x, ushort* __restrict__ Ab) {
  int g = blockIdx.x * 256 + threadIdx.x;        // 0..1048575
  float4 v = *(const float4*)&x[(size_t)g * 4];
  int m = g >> 5;
  int kin = (g & 31) * 4;
  ushort4 o;
  o.x = f2bf(v.x); o.y = f2bf(v.y); o.z = f2bf(v.z); o.w = f2bf(v.w);
  *(ushort4*)&Ab[(size_t)m * 256 + 128 + kin] = o;
}

// ---------------------------------------------------------------------------
// Kernel A4: gather  A[n, 0:128] = bf16( sum_j w_j * xbf16[src_j,:] )
// ---------------------------------------------------------------------------
__global__ __launch_bounds__(256) void gather_ell(
    const int* __restrict__ deg, const int* __restrict__ ebs,
    const float* __restrict__ ebw, ushort* __restrict__ Ab) {
  int n = blockIdx.x * 4 + (threadIdx.x >> 6);
  int lane = threadIdx.x & 63;
  int d = deg[n]; if (d > ELLCAP) d = ELLCAP;
  const int*   es = ebs + (size_t)n * ELLCAP;
  const float* wsr = ebw + (size_t)n * ELLCAP;
  float ax = 0.f, ay = 0.f;
  int j = 0;
  for (; j + 1 < d; j += 2) {
    int s0 = es[j], s1 = es[j + 1];
    float w0 = wsr[j], w1 = wsr[j + 1];
    ushort2 u0 = *(const ushort2*)&Ab[(size_t)s0 * 256 + 128 + lane * 2];
    ushort2 u1 = *(const ushort2*)&Ab[(size_t)s1 * 256 + 128 + lane * 2];
    ax += w0 * bf2f(u0.x) + w1 * bf2f(u1.x);
    ay += w0 * bf2f(u0.y) + w1 * bf2f(u1.y);
  }
  if (j < d) {
    int s0 = es[j];
    float w0 = wsr[j];
    ushort2 u0 = *(const ushort2*)&Ab[(size_t)s0 * 256 + 128 + lane * 2];
    ax += w0 * bf2f(u0.x);
    ay += w0 * bf2f(u0.y);
  }
  ushort2 o; o.x = f2bf(ax); o.y = f2bf(ay);
  *(ushort2*)&Ab[(size_t)n * 256 + lane * 2] = o;
}

// ---------------------------------------------------------------------------
// Kernel A6: Bb[n][k] = bf16 of [Wrel1;Wroot1][k][n]  (pre-transposed weights)
// ---------------------------------------------------------------------------
__global__ __launch_bounds__(256) void cast_w(
    const float* __restrict__ Wrel, const float* __restrict__ Wroot,
    ushort* __restrict__ Bb) {
  int g = blockIdx.x * 256 + threadIdx.x;        // 0..131071
  int n = g & 511, k = g >> 9;
  float w = (k < 128) ? Wrel[k * 512 + n] : Wroot[(k - 128) * 512 + n];
  Bb[n * 256 + k] = f2bf(w);
}

// ---------------------------------------------------------------------------
// Kernel C: single-stage MFMA GEMM. 64x64 tile, FULL K=256 staged once,
// ONE barrier, XOR-swizzled LDS, XCD-partitioned grid (unchanged from R10).
// ---------------------------------------------------------------------------
__global__ __launch_bounds__(256) void gemm_mfma(
    const ushort* __restrict__ Ab, const ushort* __restrict__ Bb,
    const float* __restrict__ brel, ushort* __restrict__ hw) {
  __shared__ ushort As[64 * 256];   // 32 KB
  __shared__ ushort Bs[64 * 256];   // 32 KB
  int tid = threadIdx.x;
  int blk = blockIdx.x;
  int xcd = blk & 7;
  int idx = blk >> 3;                  // 0..511
  int by = xcd * 64 + (idx & 63);      // 0..511
  int bx = idx >> 6;                   // 0..7
  int m0 = by * 64, n0 = bx * 64;

#pragma unroll
  for (int i = 0; i < 8; ++i) {
    int g = tid + i * 256;
    int r = g >> 5, c = g & 31;
    int cs = c ^ (r & 31);
    *(uint4*)&As[(r * 32 + cs) * 8] = *(const uint4*)&Ab[(size_t)(m0 + r) * 256 + c * 8];
    *(uint4*)&Bs[(r * 32 + cs) * 8] = *(const uint4*)&Bb[(size_t)(n0 + r) * 256 + c * 8];
  }
  __syncthreads();

  int wave = tid >> 6, lane = tid & 63;
  int wm = (wave >> 1) * 32, wn = (wave & 1) * 32;
  int l16 = lane & 15, quad = lane >> 4;

  f32x4_t acc[2][2];
#pragma unroll
  for (int f = 0; f < 2; ++f)
#pragma unroll
    for (int g = 0; g < 2; ++g) acc[f][g] = (f32x4_t){0.f, 0.f, 0.f, 0.f};

  int arow[2], brow[2];
#pragma unroll
  for (int f = 0; f < 2; ++f) {
    arow[f] = wm + f * 16 + l16;
    brow[f] = wn + f * 16 + l16;
  }

#pragma unroll
  for (int kc = 0; kc < 8; ++kc) {
    int cl = kc * 4 + quad;
    bf16x8_t af[2], bf[2];
#pragma unroll
    for (int f = 0; f < 2; ++f) {
      af[f] = *(const bf16x8_t*)&As[(arow[f] * 32 + (cl ^ (arow[f] & 31))) * 8];
      bf[f] = *(const bf16x8_t*)&Bs[(brow[f] * 32 + (cl ^ (brow[f] & 31))) * 8];
    }
#pragma unroll
    for (int f = 0; f < 2; ++f)
#pragma unroll
      for (int g = 0; g < 2; ++g)
        acc[f][g] = __builtin_amdgcn_mfma_f32_16x16x32_bf16(af[f], bf[g], acc[f][g], 0, 0, 0);
  }

#pragma unroll
  for (int g = 0; g < 2; ++g) {
    int col = n0 + wn + g * 16 + l16;
    float bias = brel[col];
#pragma unroll
    for (int f = 0; f < 2; ++f) {
      int rowb = m0 + wm + f * 16 + quad * 4;
#pragma unroll
      for (int r = 0; r < 4; ++r) {
        float v = fmaxf(acc[f][g][r] + bias, 0.f);
        hw[(size_t)(rowb + r) * 512 + col] = f2bf(v);
      }
    }
  }
}

// ---------------------------------------------------------------------------
// Kernel D+F fused: per node compute s (softmax of h.Wpool+b), store s and
// s_logits, and accumulate out[b,c,:] partials IN REGISTERS; block partials
// plain-stored to outpart (no atomics). ss accumulators: 3 atomics/block.
// Grid 512 blocks x 64 nodes (wave handles 16 nodes). h read ONCE.
// ---------------------------------------------------------------------------
__global__ __launch_bounds__(256) void pool_node(
    const ushort* __restrict__ hw, const float* __restrict__ Wp,
    const float* __restrict__ bp, float* __restrict__ s,
    float* __restrict__ slog, float* __restrict__ outpart,
    float* __restrict__ ssacc) {
  __shared__ float red[4][1024];   // 16 KB: per-wave partials (o0|o1)
  __shared__ float ssr[4][3];
  int blk = blockIdx.x;            // 512 blocks
  int b = blk >> 6;                // 64 blocks per graph
  int wave = threadIdx.x >> 6, lane = threadIdx.x & 63;
  int n0 = blk * 64 + wave * 16;
  int f0 = lane * 8;

  float wp0[8], wp1[8];
#pragma unroll
  for (int j = 0; j < 8; ++j) {
    wp0[j] = Wp[(f0 + j) * 2];
    wp1[j] = Wp[(f0 + j) * 2 + 1];
  }
  float bp0 = bp[0], bp1 = bp[1];
  float o0[8] = {0, 0, 0, 0, 0, 0, 0, 0};
  float o1[8] = {0, 0, 0, 0, 0, 0, 0, 0};
  float sa = 0.f, sb = 0.f, sc2 = 0.f;

  for (int i = 0; i < 16; ++i) {
    int n = n0 + i;
    bf16x8_t hv = *(const bf16x8_t*)&hw[(size_t)n * HID + f0];
    float h[8];
    float a0 = 0.f, a1 = 0.f;
#pragma unroll
    for (int j = 0; j < 8; ++j) {
      h[j] = bf2f(((ushort)__builtin_bit_cast(short, (short)0), (ushort)0) | 0);  // placeholder removed below
    }
    // convert bf16x8 -> float via bit ops
    {
      const ushort* hp = (const ushort*)&hv;
#pragma unroll
      for (int j = 0; j < 8; ++j) h[j] = bf2f(hp[j]);
    }
#pragma unroll
    for (int j = 0; j < 8; ++j) {
      a0 += h[j] * wp0[j];
      a1 += h[j] * wp1[j];
    }
#pragma unroll
    for (int off = 32; off; off >>= 1) {
      a0 += __shfl_down(a0, off, 64);
      a1 += __shfl_down(a1, off, 64);
    }
    float s0 = 0.f, s1 = 0.f;
    if (lane == 0) {
      float l0 = a0 + bp0, l1 = a1 + bp1;
      slog[n * 2] = l0;
      slog[n * 2 + 1] = l1;
      float m = fmaxf(l0, l1);
      float e0 = expf(l0 - m), e1 = expf(l1 - m);
      float inv = 1.f / (e0 + e1);
      s0 = e0 * inv; s1 = e1 * inv;
      s[n * 2] = s0;
      s[n * 2 + 1] = s1;
      sa += s0 * s0; sb += s0 * s1; sc2 += s1 * s1;
    }
    s0 = __shfl(s0, 0, 64);
    s1 = __shfl(s1, 0, 64);
#pragma unroll
    for (int j = 0; j < 8; ++j) {
      o0[j] += s0 * h[j];
      o1[j] += s1 * h[j];
    }
  }

#pragma unroll
  for (int j = 0; j < 8; ++j) {
    red[wave][f0 + j] = o0[j];
    red[wave][512 + f0 + j] = o1[j];
  }
  if (lane == 0) { ssr[wave][0] = sa; ssr[wave][1] = sb; ssr[wave][2] = sc2; }
  __syncthreads();
  int t = threadIdx.x;
#pragma unroll
  for (int q = 0; q < 4; ++q) {
    int idx = t + q * 256;
    float v = red[0][idx] + red[1][idx] + red[2][idx] + red[3][idx];
    outpart[(size_t)blk * 1024 + idx] = v;
  }
  if (t < 3) {
    float v = ssr[0][t] + ssr[1][t] + ssr[2][t] + ssr[3][t];
    atomicAdd(&ssacc[b * 4 + t], v);
  }
}

// ---------------------------------------------------------------------------
// Kernel E: out_adj_raw[b,i,j] = sum_e w_e * s[src,i] * s[dst,j]
// + mincut_den[b] = sum_e w_e * (s0[src]^2 + s1[src]^2)
// ---------------------------------------------------------------------------
__global__ __launch_bounds__(256) void edge_pass2(
    const int* __restrict__ src, const int* __restrict__ dst,
    const float* __restrict__ ew, const float* __restrict__ s,
    float* __restrict__ oadj, float* __restrict__ mden) {
  int b = blockIdx.x >> 6;
  int sub = blockIdx.x & 63;
  int base = b * EE + sub * 1024;
  float p00 = 0, p01 = 0, p10 = 0, p11 = 0, md = 0;
  for (int i = threadIdx.x; i < 1024; i += 256) {
    int e = base + i;
    int r = src[e], c = dst[e];
    float w = ew[e];
    float s0r = s[r * 2], s1r = s[r * 2 + 1];
    float s0c = s[c * 2], s1c = s[c * 2 + 1];
    p00 += w * s0r * s0c; p01 += w * s0r * s1c;
    p10 += w * s1r * s0c; p11 += w * s1r * s1c;
    md  += w * (s0r * s0r + s1r * s1r);
  }
#pragma unroll
  for (int off = 32; off; off >>= 1) {
    p00 += __shfl_down(p00, off, 64);
    p01 += __shfl_down(p01, off, 64);
    p10 += __shfl_down(p10, off, 64);
    p11 += __shfl_down(p11, off, 64);
    md  += __shfl_down(md,  off, 64);
  }
  __shared__ float red[4][5];
  int wave = threadIdx.x >> 6, lane = threadIdx.x & 63;
  if (lane == 0) {
    red[wave][0] = p00; red[wave][1] = p01;
    red[wave][2] = p10; red[wave][3] = p11;
    red[wave][4] = md;
  }
  __syncthreads();
  if (threadIdx.x < 4) {
    float v = red[0][threadIdx.x] + red[1][threadIdx.x] +
              red[2][threadIdx.x] + red[3][threadIdx.x];
    atomicAdd(&oadj[b * 4 + threadIdx.x], v);
  } else if (threadIdx.x == 4) {
    float v = red[0][4] + red[1][4] + red[2][4] + red[3][4];
    atomicAdd(&mden[b], v);
  }
}

// ---------------------------------------------------------------------------
// Kernel G1: per-graph scalars + build u,v vectors (sums outpart partials).
// ---------------------------------------------------------------------------
__global__ __launch_bounds__(256) void finalize_a(
    const float* __restrict__ outpart, const float* __restrict__ oadj,
    const float* __restrict__ ssacc, const float* __restrict__ mden,
    float* __restrict__ uv, float* __restrict__ dout) {
  __shared__ float sc[2];
  int b = blockIdx.x, t = threadIdx.x;
  if (t == 0) {
    float r00 = oadj[b * 4 + 0], r01 = oadj[b * 4 + 1];
    float r10 = oadj[b * 4 + 2], r11 = oadj[b * 4 + 3];
    atomicAdd(&dout[80], -((r00 + r11) / mden[b]) / (float)BB);
    float a = ssacc[b * 4 + 0], bb = ssacc[b * 4 + 1], c = ssacc[b * 4 + 2];
    float nrm = sqrtf(a * a + 2.f * bb * bb + c * c);
    float q = 0.70710678118654752f;
    float da = a / nrm - q, db = bb / nrm, dc = c / nrm - q;
    atomicAdd(&dout[81], sqrtf(da * da + 2.f * db * db + dc * dc) / (float)BB);
    float d20 = sqrtf(r01) + 1e-15f;
    float d21 = sqrtf(r10) + 1e-15f;
    float oa01 = r01 / (d20 * d21);
    float oa10 = r10 / (d21 * d20);
    dout[65618 + b * 4 + 0] = 0.f;
    dout[65618 + b * 4 + 1] = oa01;
    dout[65618 + b * 4 + 2] = oa10;
    dout[65618 + b * 4 + 3] = 0.f;
    sc[0] = oa01; sc[1] = oa10;
  }
  __syncthreads();
  float oa01 = sc[0], oa10 = sc[1];
  for (int f = t; f < HID; f += 256) {
    float o0 = 0.f, o1 = 0.f;
    for (int i = 0; i < 64; ++i) {
      o0 += outpart[(size_t)(b * 64 + i) * 1024 + f];
      o1 += outpart[(size_t)(b * 64 + i) * 1024 + 512 + f];
    }
    uv[b * HID + f] = oa10 * o1 + oa01 * o0;           // u
    uv[BB * HID + b * HID + f] = o0 + o1;              // v
  }
}

// ---------------------------------------------------------------------------
// Kernel G2: conv3 split-K partials. Grid 128 = kc(16) x fc(8).
// ---------------------------------------------------------------------------
__global__ __launch_bounds__(256) void conv3_part(
    const float* __restrict__ uv, const float* __restrict__ Wrel3,
    const float* __restrict__ Wroot3, float* __restrict__ xmacc) {
  __shared__ float us[8][32], vs[8][32];
  __shared__ float red[4][64][8];
  int blk = blockIdx.x;
  int fc = blk & 7, kc = blk >> 3;
  int t = threadIdx.x;
  {
    int b = t >> 5, k = t & 31;
    us[b][k] = uv[b * HID + kc * 32 + k];
    vs[b][k] = uv[BB * HID + b * HID + kc * 32 + k];
  }
  __syncthreads();
  int f = fc * 64 + (t & 63);
  int ks = t >> 6;                 // 0..3
  float acc[8] = {0, 0, 0, 0, 0, 0, 0, 0};
#pragma unroll
  for (int j = 0; j < 8; ++j) {
    int kl = ks * 8 + j;           // 0..31
    int k = kc * 32 + kl;
    float wr = Wrel3[k * HID + f];
    float wo = Wroot3[k * HID + f];
#pragma unroll
    for (int b = 0; b < 8; ++b)
      acc[b] += us[b][kl] * wr + vs[b][kl] * wo;
  }
#pragma unroll
  for (int b = 0; b < 8; ++b) red[ks][t & 63][b] = acc[b];
  __syncthreads();
  if (ks == 0) {
    int fl = t & 63;
#pragma unroll
    for (int b = 0; b < 8; ++b) {
      float v = red[0][fl][b] + red[1][fl][b] + red[2][fl][b] + red[3][fl][b];
      atomicAdd(&xmacc[b * HID + f], v);
    }
  }
}

// ---------------------------------------------------------------------------
// Kernel G3: lin1 split-K partials; xm = 0.5*xmacc + brel3 at staging.
// ---------------------------------------------------------------------------
__global__ __launch_bounds__(256) void lin1_part(
    const float* __restrict__ xmacc, const float* __restrict__ brel3,
    const float* __restrict__ Wlin1, float* __restrict__ h2acc) {
  __shared__ float xs[8][32];
  __shared__ float red[4][64][8];
  int blk = blockIdx.x;
  int fc = blk & 7, kc = blk >> 3;
  int t = threadIdx.x;
  {
    int b = t >> 5, k = t & 31;
    xs[b][k] = 0.5f * xmacc[b * HID + kc * 32 + k] + brel3[kc * 32 + k];
  }
  __syncthreads();
  int f = fc * 64 + (t & 63);
  int ks = t >> 6;
  float acc[8] = {0, 0, 0, 0, 0, 0, 0, 0};
#pragma unroll
  for (int j = 0; j < 8; ++j) {
    int kl = ks * 8 + j;
    int k = kc * 32 + kl;
    float w = Wlin1[k * HID + f];
#pragma unroll
    for (int b = 0; b < 8; ++b)
      acc[b] += xs[b][kl] * w;
  }
#pragma unroll
  for (int b = 0; b < 8; ++b) red[ks][t & 63][b] = acc[b];
  __syncthreads();
  if (ks == 0) {
    int fl = t & 63;
#pragma unroll
    for (int b = 0; b < 8; ++b) {
      float v = red[0][fl][b] + red[1][fl][b] + red[2][fl][b] + red[3][fl][b];
      atomicAdd(&h2acc[b * HID + f], v);
    }
  }
}

// ---------------------------------------------------------------------------
// Kernel G4: logits + log_softmax; h2 = relu(h2acc + blin1) at staging.
// ---------------------------------------------------------------------------
__global__ __launch_bounds__(256) void head(
    const float* __restrict__ h2acc, const float* __restrict__ blin1,
    const float* __restrict__ Wlin2, const float* __restrict__ blin2,
    float* __restrict__ dout) {
  __shared__ float hs[HID];
  __shared__ float lg[16];
  __shared__ float lse;
  int b = blockIdx.x, t = threadIdx.x;
  for (int i = t; i < HID; i += 256)
    hs[i] = fmaxf(h2acc[b * HID + i] + blin1[i], 0.f);
  __syncthreads();
  int wave = t >> 6, lane = t & 63;
  for (int o = wave; o < OUTC; o += 4) {
    float acc = 0.f;
    for (int k = lane; k < HID; k += 64)
      acc += hs[k] * Wlin2[k * OUTC + o];
#pragma unroll
    for (int off = 32; off; off >>= 1) acc += __shfl_down(acc, off, 64);
    if (lane == 0) lg[o] = acc + blin2[o];
  }
  __syncthreads();
  if (t == 0) {
    float m = lg[0];
    for (int o = 1; o < OUTC; ++o) m = fmaxf(m, lg[o]);
    float se = 0.f;
    for (int o = 0; o < OUTC; ++o) se += expf(lg[o] - m);
    lse = m + logf(se);
  }
  __syncthreads();
  if (t < OUTC) dout[b * OUTC + t] = lg[t] - lse;
}

// ---------------------------------------------------------------------------
// Launcher
// ---------------------------------------------------------------------------
extern "C" void kernel_launch(void* const* d_in, const int* in_sizes, int n_in,
                              void* d_out, int out_size, void* d_ws, size_t ws_size,
                              hipStream_t stream) {
  const float* x      = (const float*)d_in[0];
  const int*   ei     = (const int*)d_in[1];
  const float* ew     = (const float*)d_in[3];
  const float* Wrel1  = (const float*)d_in[4];
  const float* brel1  = (const float*)d_in[5];
  const float* Wroot1 = (const float*)d_in[6];
  const float* Wpool  = (const float*)d_in[7];
  const float* bpool  = (const float*)d_in[8];
  const float* Wrel3  = (const float*)d_in[9];
  const float* brel3  = (const float*)d_in[10];
  const float* Wroot3 = (const float*)d_in[11];
  const float* Wlin1  = (const float*)d_in[12];
  const float* blin1  = (const float*)d_in[13];
  const float* Wlin2  = (const float*)d_in[14];
  const float* blin2  = (const float*)d_in[15];
  float* out = (float*)d_out;
  float* ws  = (float*)d_ws;

  // workspace layout (float units)
  float* oadj  = ws + 40960;                // [40960, 40992)
  float* ssacc = oadj + 32;                 // [40992, 41024)
  float* mden  = ssacc + 32;                // [41024, 41032)
  int*   deg   = (int*)(mden + 8);          // [41032, 73800)  zero-region end
  ushort* Ab   = (ushort*)(ws + 106568);    // 32768x256 bf16  [106568, 4300872)
  ushort* Bb   = (ushort*)(ws + 4300872);   // 512x256 bf16    [4300872, 4366408)
  ushort* hbf  = (ushort*)(ws + 4366408);   // 32768x512 bf16  [4366408, 12755016)
  float* xmacc = ws + 12755016;             // 4096
  float* h2acc = xmacc + 4096;              // 4096            [12759112, 12763208)
  float* outpart = ws + 12763208;           // 512*1024        [12763208, 13287496)
  // aliases (lifetimes by stream order):
  int*   ebs   = (int*)(ws + 4366408);      // 32768*64 ints (8.4MB), inside h region
  float* ebw   = ws + 4366408 + 2097152;    // 32768*64 floats — both dead before gemm writes h
  float* s     = ws + 106568;               // overlays Ab; Ab dead after gemm
  float* uv    = (float*)deg;               // deg dead after gather_ell

  const int* src = ei;
  const int* dst = ei + BE;

  // zero oadj/ssacc/mden/deg (contiguous 32840 floats) + xmacc/h2acc + losses
  hipMemsetAsync(ws + 40960, 0, (size_t)32840 * sizeof(float), stream);
  hipMemsetAsync(xmacc, 0, (size_t)8192 * sizeof(float), stream);
  hipMemsetAsync(out + 80, 0, 2 * sizeof(float), stream);

  ell_build  <<<BE / 256, 256, 0, stream>>>(src, dst, ew, deg, ebs, ebw);
  cast_x     <<<4096, 256, 0, stream>>>(x, Ab);
  cast_w     <<<512, 256, 0, stream>>>(Wrel1, Wroot1, Bb);
  gather_ell <<<BN / 4, 256, 0, stream>>>(deg, ebs, ebw, Ab);
  gemm_mfma  <<<4096, 256, 0, stream>>>(Ab, Bb, brel1, hbf);
  pool_node  <<<512, 256, 0, stream>>>(hbf, Wpool, bpool, s, out + 82, outpart, ssacc);
  edge_pass2 <<<BB * 64, 256, 0, stream>>>(src, dst, ew, s, oadj, mden);
  finalize_a <<<BB, 256, 0, stream>>>(outpart, oadj, ssacc, mden, uv, out);
  conv3_part <<<128, 256, 0, stream>>>(uv, Wrel3, Wroot3, xmacc);
  lin1_part  <<<128, 256, 0, stream>>>(xmacc, brel3, Wlin1, h2acc);
  head       <<<BB, 256, 0, stream>>>(h2acc, blin1, Wlin2, blin2, out);
}